// Round 4
// baseline (273.917 us; speedup 1.0000x reference)
//
#include <hip/hip_runtime.h>
#include <hip/hip_bf16.h>

// Dims (fixed by the problem)
#define B_   8
#define L_   256
#define D_   32
#define E_   128
#define H_   8
#define Q_   128
#define HID_ 256

// ---------------------------------------------------------------------------
// K0: per-batch time normalization, has-flag, and qt output (f32).
// grid = B, block = 256 (thread = l)
// ---------------------------------------------------------------------------
__global__ void k0_prep(const int* __restrict__ mask, const float* __restrict__ times,
                        float* __restrict__ tn, float* __restrict__ has,
                        float* __restrict__ qt_out)
{
    int b = blockIdx.x;
    int t = threadIdx.x;   // = l
    __shared__ float smin[256], smax[256];
    __shared__ float sh[2];

    const int* mrow = mask + (size_t)(b * L_ + t) * D_;
    int any = 0;
    #pragma unroll
    for (int d = 0; d < D_; ++d) any |= mrow[d];
    float tv = times[b * L_ + t];
    smin[t] = any ? tv : 1e38f;
    smax[t] = any ? tv : -1e38f;
    __syncthreads();
    for (int off = 128; off > 0; off >>= 1) {
        if (t < off) {
            smin[t] = fminf(smin[t], smin[t + off]);
            smax[t] = fmaxf(smax[t], smax[t + off]);
        }
        __syncthreads();
    }
    if (t == 0) {
        float mn = smin[0], mx = smax[0];
        float hv = (mn < 1e37f) ? 1.f : 0.f;    // any observed step in this batch?
        sh[0] = (hv > 0.f) ? mn : 0.f;
        sh[1] = (hv > 0.f) ? mx : 1.f;
        has[b] = hv;
    }
    __syncthreads();
    float inv = 1.f / fmaxf(sh[1] - sh[0], 1e-6f);
    tn[b * L_ + t] = any ? (tv - sh[0]) * inv : 0.f;

    if (t < Q_) qt_out[b * Q_ + t] = (float)t * (1.f / 127.f);
}

// ---------------------------------------------------------------------------
// K1: query-time embedding + q-projection (batch-independent, [Q,E]).
// grid = Q, block = E
// ---------------------------------------------------------------------------
__global__ void k1_qproj(const float* __restrict__ w_per, const float* __restrict__ b_per,
                         const float* __restrict__ w_lin, const float* __restrict__ b_lin,
                         const float* __restrict__ wq, const float* __restrict__ bq,
                         float* __restrict__ qproj)
{
    int q = blockIdx.x, e = threadIdx.x;
    __shared__ __align__(16) float emb[E_];
    float t = (float)q * (1.f / 127.f);
    emb[e] = (e == 0) ? (t * w_lin[0] + b_lin[0])
                      : __sinf(t * w_per[e - 1] + b_per[e - 1]);
    __syncthreads();
    const float4* wr4 = reinterpret_cast<const float4*>(wq + (size_t)e * E_);
    const float4* e4  = reinterpret_cast<const float4*>(emb);
    float acc = bq[e];
    #pragma unroll 8
    for (int j = 0; j < E_ / 4; ++j) {
        float4 w = wr4[j], x = e4[j];
        acc += w.x * x.x + w.y * x.y + w.z * x.z + w.w * x.w;
    }
    qproj[q * E_ + e] = acc;
}

// ---------------------------------------------------------------------------
// K2: key-time embedding + k-projection, 8 rows per block.
// grid = B*L/8, block = E
// ---------------------------------------------------------------------------
__global__ void k2_kproj(const float* __restrict__ tn,
                         const float* __restrict__ w_per, const float* __restrict__ b_per,
                         const float* __restrict__ w_lin, const float* __restrict__ b_lin,
                         const float* __restrict__ wk, const float* __restrict__ bk,
                         float* __restrict__ kproj)
{
    int blk = blockIdx.x, e = threadIdx.x;
    int bl0 = blk * 8;
    __shared__ __align__(16) float emb[8][E_];
    __shared__ float tsh[8];
    if (e < 8) tsh[e] = tn[bl0 + e];
    __syncthreads();
    float wp = (e == 0) ? 0.f : w_per[e - 1];
    float bp = (e == 0) ? 0.f : b_per[e - 1];
    float wl = w_lin[0], bl = b_lin[0];
    #pragma unroll
    for (int r = 0; r < 8; ++r) {
        float t = tsh[r];
        emb[r][e] = (e == 0) ? (t * wl + bl) : __sinf(t * wp + bp);
    }
    __syncthreads();
    const float4* wr4 = reinterpret_cast<const float4*>(wk + (size_t)e * E_);
    float acc[8];
    #pragma unroll
    for (int r = 0; r < 8; ++r) acc[r] = bk[e];
    for (int j = 0; j < E_ / 4; ++j) {
        float4 w = wr4[j];
        #pragma unroll
        for (int r = 0; r < 8; ++r) {
            float4 x = *reinterpret_cast<const float4*>(&emb[r][j * 4]);
            acc[r] += w.x * x.x + w.y * x.y + w.z * x.z + w.w * x.w;
        }
    }
    #pragma unroll
    for (int r = 0; r < 8; ++r) kproj[(size_t)(bl0 + r) * E_ + e] = acc[r];
}

// ---------------------------------------------------------------------------
// K3: literal per-channel masked softmax + full 512-channel context.
// One block per (b,q); 256 threads.
//   Phase 1: thread=l computes raw scores s[h][l] -> LDS.
//   Phase 2: thread=(h,d): sm = m ? s : -1e4 ; M = max_l sm ;
//            e = exp(sm - M) ; ctx_v = sum e*v / sum e ; ctx_m = sum e*m / sum e.
//   All-masked column: M = -1e4 -> all e = 1 -> uniform (matches reference).
// grid = (Q, B), block = 256
// ---------------------------------------------------------------------------
__global__ void k3_attn(const float* __restrict__ qproj, const float* __restrict__ kproj,
                        const int* __restrict__ mask, const float* __restrict__ values,
                        float* __restrict__ ctxf)
{
    int q = blockIdx.x, b = blockIdx.y;
    int tid = threadIdx.x;
    __shared__ __align__(16) float qv[E_];
    __shared__ float s_lds[H_][L_];

    if (tid < E_) qv[tid] = qproj[q * E_ + tid];
    __syncthreads();

    // Phase 1: raw scores, thread = l (=tid), all 8 heads
    const float4* kr4 = reinterpret_cast<const float4*>(kproj + (size_t)(b * L_ + tid) * E_);
    const float4* qv4 = reinterpret_cast<const float4*>(qv);
    #pragma unroll
    for (int h = 0; h < H_; ++h) {
        float acc = 0.f;
        #pragma unroll
        for (int j = 0; j < 4; ++j) {
            float4 kk = kr4[h * 4 + j], qq = qv4[h * 4 + j];
            acc += kk.x * qq.x + kk.y * qq.y + kk.z * qq.z + kk.w * qq.w;
        }
        s_lds[h][tid] = acc * 0.25f;  // 1/sqrt(EK=16)
    }
    __syncthreads();

    // Phase 2: literal per-channel masked softmax. thread = (h,d)
    int h = tid >> 5, d = tid & 31;
    const int*   mcol = mask   + (size_t)b * L_ * D_ + d;
    const float* vcol = values + (size_t)b * L_ * D_ + d;

    float M = -10000.0f;
    for (int l = 0; l < L_; ++l) {
        float sm = mcol[(size_t)l * D_] ? s_lds[h][l] : -10000.0f;
        M = fmaxf(M, sm);
    }
    float den = 0.f, av = 0.f, am = 0.f;
    for (int l = 0; l < L_; ++l) {
        int   mm = mcol[(size_t)l * D_];
        float sm = mm ? s_lds[h][l] : -10000.0f;
        float e  = __expf(sm - M);   // masked & M>-1e4: exp(-1e4-M) underflows to 0 (= reference fp32)
        den += e;
        av  += e * vcol[(size_t)l * D_];
        am  += e * (float)mm;
    }
    float inv = 1.f / den;
    size_t rowoff = (size_t)(b * Q_ + q) * 512;
    ctxf[rowoff + h * 64 + d]      = av * inv;   // value channel h*64+d
    ctxf[rowoff + h * 64 + 32 + d] = am * inv;   // mask  channel h*64+32+d
}

// ---------------------------------------------------------------------------
// K4a: transpose wo: wot[C][hid] = wo[hid][C], all 512 channels.
// grid = 512 (C), block = HID
// ---------------------------------------------------------------------------
__global__ void k_wot(const float* __restrict__ wo, float* __restrict__ wot)
{
    int C = blockIdx.x, hid = threadIdx.x;
    wot[(size_t)C * HID_ + hid] = wo[(size_t)hid * 512 + C];
}

// ---------------------------------------------------------------------------
// K4b: output projection, K = 512, 4 rows per block.
// grid = B*Q/4, block = HID (thread = hid)
// ---------------------------------------------------------------------------
__global__ void k_gemm(const float* __restrict__ ctxf, const float* __restrict__ wot,
                       const float* __restrict__ bo, float* __restrict__ seq_pre)
{
    int row0 = blockIdx.x * 4;          // row = b*Q + q
    int hid = threadIdx.x;
    __shared__ __align__(16) float a[4][512];
    #pragma unroll
    for (int i = 0; i < 4; ++i) {
        a[i][hid]       = ctxf[(size_t)(row0 + i) * 512 + hid];
        a[i][hid + 256] = ctxf[(size_t)(row0 + i) * 512 + hid + 256];
    }
    __syncthreads();
    float bias = bo[hid];
    float acc0 = bias, acc1 = bias, acc2 = bias, acc3 = bias;
    for (int c4 = 0; c4 < 128; ++c4) {
        float w0 = wot[(size_t)(c4 * 4 + 0) * HID_ + hid];
        float w1 = wot[(size_t)(c4 * 4 + 1) * HID_ + hid];
        float w2 = wot[(size_t)(c4 * 4 + 2) * HID_ + hid];
        float w3 = wot[(size_t)(c4 * 4 + 3) * HID_ + hid];
        float4 a0 = *reinterpret_cast<const float4*>(&a[0][c4 * 4]);
        float4 a1 = *reinterpret_cast<const float4*>(&a[1][c4 * 4]);
        float4 a2 = *reinterpret_cast<const float4*>(&a[2][c4 * 4]);
        float4 a3 = *reinterpret_cast<const float4*>(&a[3][c4 * 4]);
        acc0 += a0.x * w0 + a0.y * w1 + a0.z * w2 + a0.w * w3;
        acc1 += a1.x * w0 + a1.y * w1 + a1.z * w2 + a1.w * w3;
        acc2 += a2.x * w0 + a2.y * w1 + a2.z * w2 + a2.w * w3;
        acc3 += a3.x * w0 + a3.y * w1 + a3.z * w2 + a3.w * w3;
    }
    seq_pre[(size_t)(row0 + 0) * HID_ + hid] = acc0;
    seq_pre[(size_t)(row0 + 1) * HID_ + hid] = acc1;
    seq_pre[(size_t)(row0 + 2) * HID_ + hid] = acc2;
    seq_pre[(size_t)(row0 + 3) * HID_ + hid] = acc3;
}

// ---------------------------------------------------------------------------
// K5: two-pass LayerNorm per row + has-mask, f32 store.
// grid = B*Q, block = HID
// ---------------------------------------------------------------------------
__global__ void k_ln(const float* __restrict__ seq_pre, const float* __restrict__ ln_g,
                     const float* __restrict__ ln_b, const float* __restrict__ has,
                     float* __restrict__ seq_out)
{
    int row = blockIdx.x, hid = threadIdx.x;
    __shared__ float red[HID_];
    __shared__ float sval[2];

    float x = seq_pre[(size_t)row * HID_ + hid];
    red[hid] = x;
    __syncthreads();
    for (int off = 128; off > 0; off >>= 1) {
        if (hid < off) red[hid] += red[hid + off];
        __syncthreads();
    }
    if (hid == 0) sval[0] = red[0] * (1.f / HID_);
    __syncthreads();
    float mu = sval[0];
    float dx = x - mu;
    red[hid] = dx * dx;
    __syncthreads();
    for (int off = 128; off > 0; off >>= 1) {
        if (hid < off) red[hid] += red[hid + off];
        __syncthreads();
    }
    if (hid == 0) sval[1] = rsqrtf(red[0] * (1.f / HID_) + 1e-5f);
    __syncthreads();
    float outv = (dx * sval[1] * ln_g[hid] + ln_b[hid]) * has[row >> 7];
    seq_out[(size_t)row * HID_ + hid] = outv;
}

// ---------------------------------------------------------------------------
// K6: pooled = mean over Q of seq (f32).
// grid = B, block = HID
// ---------------------------------------------------------------------------
__global__ void k_pool(const float* __restrict__ seq, float* __restrict__ pooled)
{
    int b = blockIdx.x, hid = threadIdx.x;
    float s = 0.f;
    for (int q = 0; q < Q_; ++q)
        s += seq[((size_t)b * Q_ + q) * HID_ + hid];
    pooled[b * HID_ + hid] = s * (1.f / (float)Q_);
}

// ---------------------------------------------------------------------------
extern "C" void kernel_launch(void* const* d_in, const int* in_sizes, int n_in,
                              void* d_out, int out_size, void* d_ws, size_t ws_size,
                              hipStream_t stream)
{
    const float* values = (const float*)d_in[0];
    const int*   mask   = (const int*)  d_in[1];
    const float* times  = (const float*)d_in[2];
    const float* w_per  = (const float*)d_in[3];
    const float* b_per  = (const float*)d_in[4];
    const float* w_lin  = (const float*)d_in[5];
    const float* b_lin  = (const float*)d_in[6];
    const float* wq     = (const float*)d_in[7];
    const float* bq     = (const float*)d_in[8];
    const float* wk     = (const float*)d_in[9];
    const float* bk     = (const float*)d_in[10];
    const float* wo     = (const float*)d_in[11];
    const float* bo     = (const float*)d_in[12];
    const float* ln_g   = (const float*)d_in[13];
    const float* ln_b   = (const float*)d_in[14];

    // Reference output dtype is float32 -> d_out is float*.
    float* out     = (float*)d_out;
    float* seq_out = out;                        // B*Q*HID = 262144
    float* pooled  = out + 262144;               // B*HID   = 2048
    float* qt_out  = out + 262144 + 2048;        // B*Q     = 1024

    float* ws      = (float*)d_ws;
    float* tn      = ws;              // 2048
    float* has     = ws + 2048;       // 8
    float* qproj   = ws + 2056;       // 16384   (byte off 8224, 16B-aligned)
    float* kproj   = ws + 18440;      // 262144  (dead after k3)
    float* ctxf    = ws + 280584;     // 524288  full 512-channel context
    float* wot     = ws + 804872;     // 131072
    float* seq_pre = ws + 18440;      // 262144  aliases kproj (safe: k3 done before k_gemm)

    k0_prep <<<B_,           256,  0, stream>>>(mask, times, tn, has, qt_out);
    k1_qproj<<<Q_,           E_,   0, stream>>>(w_per, b_per, w_lin, b_lin, wq, bq, qproj);
    k2_kproj<<<B_ * L_ / 8,  E_,   0, stream>>>(tn, w_per, b_per, w_lin, b_lin, wk, bk, kproj);
    k_wot   <<<512,          HID_, 0, stream>>>(wo, wot);
    k3_attn <<<dim3(Q_, B_), 256,  0, stream>>>(qproj, kproj, mask, values, ctxf);
    k_gemm  <<<B_ * Q_ / 4,  HID_, 0, stream>>>(ctxf, wot, bo, seq_pre);
    k_ln    <<<B_ * Q_,      HID_, 0, stream>>>(seq_pre, ln_g, ln_b, has, seq_out);
    k_pool  <<<B_,           HID_, 0, stream>>>(seq_out, pooled);
}

// Round 6
// 176.271 us; speedup vs baseline: 1.5539x; 1.5539x over previous
//
#include <hip/hip_runtime.h>
#include <hip/hip_bf16.h>

// Dims (fixed by the problem)
#define B_   8
#define L_   256
#define D_   32
#define E_   128
#define H_   8
#define Q_   128
#define HID_ 256

// ---------------------------------------------------------------------------
// kA: fused prep. Blocks 0..7: per-batch prep (tn, has, mvm, bitsT, colmean,
//     cm, qt_out, pooled zero). Blocks 8..71: q-projection (2 q per block).
// block = 256 threads
// ---------------------------------------------------------------------------
__global__ __launch_bounds__(256) void kA_prep(
    const float* __restrict__ values, const int* __restrict__ mask,
    const float* __restrict__ times,
    const float* __restrict__ w_per, const float* __restrict__ b_per,
    const float* __restrict__ w_lin, const float* __restrict__ b_lin,
    const float* __restrict__ wq, const float* __restrict__ bq,
    float* __restrict__ tn, float* __restrict__ has,
    float* __restrict__ cm, float* __restrict__ colmean,
    float* __restrict__ mvm, unsigned* __restrict__ bitsT,
    float* __restrict__ qproj, float* __restrict__ qt_out,
    float* __restrict__ pooled)
{
    __shared__ float val_s[256][33];     // raw values (for colmean), padded
    __shared__ float smin[256], smax[256];
    __shared__ unsigned bits_s[256];     // [d][w] = [32][8]
    __shared__ float sh[2];
    __shared__ __align__(16) float emb_s[2][E_];

    int blk = blockIdx.x;
    int t = threadIdx.x;

    if (blk < B_) {
        int b = blk;                       // thread t = l
        const int*   mrow = mask   + (size_t)(b * L_ + t) * D_;
        const float* vrow = values + (size_t)(b * L_ + t) * D_;
        int4  m4[8];
        float4 v4[8];
        int any = 0;
        #pragma unroll
        for (int j = 0; j < 8; ++j) {
            m4[j] = reinterpret_cast<const int4*>(mrow)[j];
            v4[j] = reinterpret_cast<const float4*>(vrow)[j];
            any |= m4[j].x | m4[j].y | m4[j].z | m4[j].w;
            float4 mv;
            mv.x = m4[j].x ? v4[j].x : 0.f;
            mv.y = m4[j].y ? v4[j].y : 0.f;
            mv.z = m4[j].z ? v4[j].z : 0.f;
            mv.w = m4[j].w ? v4[j].w : 0.f;
            reinterpret_cast<float4*>(mvm + (size_t)(b * L_ + t) * D_)[j] = mv;
            val_s[t][j * 4 + 0] = v4[j].x;
            val_s[t][j * 4 + 1] = v4[j].y;
            val_s[t][j * 4 + 2] = v4[j].z;
            val_s[t][j * 4 + 3] = v4[j].w;
        }
        // transposed mask bitmaps: bitsT[b][d][w], bit (l&63) of wave ballot
        int wave = t >> 6;
        #pragma unroll
        for (int d = 0; d < D_; ++d) {
            int comp;
            { int j = d >> 2, c = d & 3;
              int4 mm = m4[j];
              comp = (c == 0) ? mm.x : (c == 1) ? mm.y : (c == 2) ? mm.z : mm.w; }
            unsigned long long bal = __ballot(comp != 0);
            if ((t & 63) == 0) {
                bits_s[d * 8 + wave * 2 + 0] = (unsigned)(bal & 0xffffffffull);
                bits_s[d * 8 + wave * 2 + 1] = (unsigned)(bal >> 32);
            }
        }
        // time min/max over observed steps
        float tv = times[b * L_ + t];
        smin[t] = any ? tv : 1e38f;
        smax[t] = any ? tv : -1e38f;
        __syncthreads();
        for (int off = 128; off > 0; off >>= 1) {
            if (t < off) {
                smin[t] = fminf(smin[t], smin[t + off]);
                smax[t] = fmaxf(smax[t], smax[t + off]);
            }
            __syncthreads();
        }
        if (t == 0) {
            float mn = smin[0], mx = smax[0];
            float hv = (mn < 1e37f) ? 1.f : 0.f;
            sh[0] = (hv > 0.f) ? mn : 0.f;
            sh[1] = (hv > 0.f) ? mx : 1.f;
            has[b] = hv;
        }
        __syncthreads();
        float inv = 1.f / fmaxf(sh[1] - sh[0], 1e-6f);
        tn[b * L_ + t] = any ? (tv - sh[0]) * inv : 0.f;

        if (t < Q_) qt_out[b * Q_ + t] = (float)t * (1.f / 127.f);
        pooled[b * HID_ + t] = 0.f;                 // zero for kC atomics

        // copy bits to global; colmean + cm
        if (t < 256) bitsT[b * 256 + t] = bits_s[t];
        if (t < D_) {
            float s = 0.f;
            for (int l = 0; l < L_; ++l) s += val_s[l][t];
            colmean[b * D_ + t] = s * (1.f / (float)L_);
            unsigned o = 0;
            #pragma unroll
            for (int w = 0; w < 8; ++w) o |= bits_s[t * 8 + w];
            cm[b * D_ + t] = o ? 1.f : 0.f;
        }
    } else {
        // q-projection: 2 q per block
        int w2 = blk - B_;
        int half = t >> 7, e = t & 127;
        int q = w2 * 2 + half;
        float tt = (float)q * (1.f / 127.f);
        emb_s[half][e] = (e == 0) ? (tt * w_lin[0] + b_lin[0])
                                  : __sinf(tt * w_per[e - 1] + b_per[e - 1]);
        __syncthreads();
        const float4* wr4 = reinterpret_cast<const float4*>(wq + (size_t)e * E_);
        const float4* e4  = reinterpret_cast<const float4*>(emb_s[half]);
        float acc = bq[e];
        #pragma unroll 8
        for (int j = 0; j < E_ / 4; ++j) {
            float4 w = wr4[j], x = e4[j];
            acc += w.x * x.x + w.y * x.y + w.z * x.z + w.w * x.w;
        }
        qproj[q * E_ + e] = acc;
    }
}

// ---------------------------------------------------------------------------
// kB: blocks 0..255: k-projection (8 rows/block). Blocks 256..1279: wo
//     transpose (wot[C][hid] = wo[hid][C]). block = 128 threads
// ---------------------------------------------------------------------------
__global__ __launch_bounds__(128) void kB_kproj_wot(
    const float* __restrict__ tn,
    const float* __restrict__ w_per, const float* __restrict__ b_per,
    const float* __restrict__ w_lin, const float* __restrict__ b_lin,
    const float* __restrict__ wk, const float* __restrict__ bk,
    const float* __restrict__ wo,
    float* __restrict__ kproj, float* __restrict__ wot)
{
    int blk = blockIdx.x;
    if (blk < 256) {
        int e = threadIdx.x;
        int bl0 = blk * 8;
        __shared__ __align__(16) float emb[8][E_];
        __shared__ float tsh[8];
        if (e < 8) tsh[e] = tn[bl0 + e];
        __syncthreads();
        float wp = (e == 0) ? 0.f : w_per[e - 1];
        float bp = (e == 0) ? 0.f : b_per[e - 1];
        float wl = w_lin[0], bl = b_lin[0];
        #pragma unroll
        for (int r = 0; r < 8; ++r) {
            float tt = tsh[r];
            emb[r][e] = (e == 0) ? (tt * wl + bl) : __sinf(tt * wp + bp);
        }
        __syncthreads();
        const float4* wr4 = reinterpret_cast<const float4*>(wk + (size_t)e * E_);
        float acc[8];
        #pragma unroll
        for (int r = 0; r < 8; ++r) acc[r] = bk[e];
        for (int j = 0; j < E_ / 4; ++j) {
            float4 w = wr4[j];
            #pragma unroll
            for (int r = 0; r < 8; ++r) {
                float4 x = *reinterpret_cast<const float4*>(&emb[r][j * 4]);
                acc[r] += w.x * x.x + w.y * x.y + w.z * x.z + w.w * x.w;
            }
        }
        #pragma unroll
        for (int r = 0; r < 8; ++r) kproj[(size_t)(bl0 + r) * E_ + e] = acc[r];
    } else {
        int w = blk - 256;                 // 0..1023
        int C = w >> 1, half = w & 1;
        int hid = half * 128 + threadIdx.x;
        wot[(size_t)C * HID_ + hid] = wo[(size_t)hid * 512 + C];
    }
}

// ---------------------------------------------------------------------------
// k3: fused scores + softmax + context, LDS-resident.
//   Phase 1 (thread=l): s[h][l]; per-head global max; e = exp(s - G_h).
//   Phase 2 (thread=(h,d)): av = sum e*mvm, den = sum e*mbit (bits in regs).
//   ctx_v = cm? av/den : colmean ; ctx_m = cm? 1 : 0 (not stored; kC rebuilds).
// grid = (Q, B), block = 256
// ---------------------------------------------------------------------------
__global__ __launch_bounds__(256) void k3_attn(
    const float* __restrict__ qproj, const float* __restrict__ kproj,
    const float* __restrict__ mvm, const unsigned* __restrict__ bitsT,
    const float* __restrict__ cm, const float* __restrict__ colmean,
    float* __restrict__ ctxv)
{
    int q = blockIdx.x, b = blockIdx.y;
    int tid = threadIdx.x;
    __shared__ __align__(16) float mvm_s[L_ * D_];   // 32 KB
    __shared__ float e_s[H_][L_];                    // 8 KB
    __shared__ __align__(16) float qv_s[E_];
    __shared__ unsigned bits_s[256];
    __shared__ float gmax_s[H_];

    // stage: mvm (coalesced float4), bits, qv
    {
        const float4* src = reinterpret_cast<const float4*>(mvm + (size_t)b * L_ * D_);
        float4* dst = reinterpret_cast<float4*>(mvm_s);
        #pragma unroll
        for (int j = 0; j < 8; ++j) dst[tid + j * 256] = src[tid + j * 256];
        bits_s[tid] = bitsT[b * 256 + tid];
        if (tid < E_) qv_s[tid] = qproj[q * E_ + tid];
    }
    __syncthreads();

    // Phase 1: scores (thread = l)
    const float4* kr4 = reinterpret_cast<const float4*>(kproj + (size_t)(b * L_ + tid) * E_);
    const float4* qv4 = reinterpret_cast<const float4*>(qv_s);
    float s[H_];
    #pragma unroll
    for (int h = 0; h < H_; ++h) {
        float acc = 0.f;
        #pragma unroll
        for (int j = 0; j < 4; ++j) {
            float4 kk = kr4[h * 4 + j], qq = qv4[h * 4 + j];
            acc += kk.x * qq.x + kk.y * qq.y + kk.z * qq.z + kk.w * qq.w;
        }
        s[h] = acc * 0.25f;                // 1/sqrt(EK=16)
        e_s[h][tid] = s[h];
    }
    __syncthreads();
    // per-head global max
    {
        int h = tid >> 5, ln = tid & 31;
        float mx = -1e30f;
        #pragma unroll
        for (int j = 0; j < 8; ++j) mx = fmaxf(mx, e_s[h][ln + j * 32]);
        #pragma unroll
        for (int off = 16; off > 0; off >>= 1) mx = fmaxf(mx, __shfl_xor(mx, off));
        if (ln == 0) gmax_s[h] = mx;
    }
    __syncthreads();
    #pragma unroll
    for (int h = 0; h < H_; ++h) e_s[h][tid] = __expf(s[h] - gmax_s[h]);
    __syncthreads();

    // Phase 2: thread = (h,d); mask bits in registers
    int h = tid >> 5, d = tid & 31;
    unsigned bw[8];
    #pragma unroll
    for (int w = 0; w < 8; ++w) bw[w] = bits_s[d * 8 + w];
    const float* eh = e_s[h];
    float av = 0.f, den = 0.f;
    #pragma unroll
    for (int w = 0; w < 8; ++w) {
        unsigned bb = bw[w];
        #pragma unroll
        for (int i = 0; i < 32; ++i) {
            int l = w * 32 + i;
            float e = eh[l];
            av  += e * mvm_s[l * D_ + d];
            den += ((bb >> i) & 1u) ? e : 0.f;
        }
    }
    float cmf = cm[b * D_ + d];
    float outv = (cmf > 0.f) ? (av / den) : colmean[b * D_ + d];
    ctxv[((size_t)(b * Q_ + q)) * 256 + h * D_ + d] = outv;
}

// ---------------------------------------------------------------------------
// kC: output projection (K=512, mask channels rebuilt from cm) + fused
//     LayerNorm + has-mask + seq store + atomic pooled accumulation.
// grid = B*Q/4, block = HID
// ---------------------------------------------------------------------------
__global__ __launch_bounds__(256) void kC_gemm_ln(
    const float* __restrict__ ctxv, const float* __restrict__ wot,
    const float* __restrict__ bo, const float* __restrict__ cm,
    const float* __restrict__ ln_g, const float* __restrict__ ln_b,
    const float* __restrict__ has,
    float* __restrict__ seq_out, float* __restrict__ pooled)
{
    int row0 = blockIdx.x * 4;              // row = b*Q + q
    int hid = threadIdx.x;
    int b = row0 >> 7;
    __shared__ __align__(16) float a[4][512];
    __shared__ float cm_s[D_];
    __shared__ float pw[4][4], pws[4][4];
    __shared__ float mu_s[4], rs_s[4];

    if (hid < D_) cm_s[hid] = (cm[b * D_ + hid] > 0.f) ? 1.f : 0.f;
    __syncthreads();

    // build A rows: channel C: h=C>>6, r=C&63; r<32 -> value (ctxv), else cm
    {
        int h1 = hid >> 6, r = hid & 63;
        float cmv = (r >= 32) ? cm_s[r - 32] : 0.f;
        #pragma unroll
        for (int i = 0; i < 4; ++i) {
            const float* crow = ctxv + (size_t)(row0 + i) * 256;
            a[i][hid]       = (r < 32) ? crow[h1 * D_ + r]       : cmv;
            a[i][hid + 256] = (r < 32) ? crow[(h1 + 4) * D_ + r] : cmv;
        }
    }
    __syncthreads();

    float bias = bo[hid];
    float acc[4];
    #pragma unroll
    for (int i = 0; i < 4; ++i) acc[i] = bias;
    for (int c4 = 0; c4 < 128; ++c4) {
        float w0 = wot[(size_t)(c4 * 4 + 0) * HID_ + hid];
        float w1 = wot[(size_t)(c4 * 4 + 1) * HID_ + hid];
        float w2 = wot[(size_t)(c4 * 4 + 2) * HID_ + hid];
        float w3 = wot[(size_t)(c4 * 4 + 3) * HID_ + hid];
        #pragma unroll
        for (int i = 0; i < 4; ++i) {
            float4 ai = *reinterpret_cast<const float4*>(&a[i][c4 * 4]);
            acc[i] += ai.x * w0 + ai.y * w1 + ai.z * w2 + ai.w * w3;
        }
    }

    // fused LayerNorm: per-row mean/var via wave shuffles + LDS combine
    int wave = hid >> 6;
    #pragma unroll
    for (int r = 0; r < 4; ++r) {
        float s = acc[r], ss = acc[r] * acc[r];
        #pragma unroll
        for (int off = 32; off > 0; off >>= 1) {
            s  += __shfl_xor(s, off);
            ss += __shfl_xor(ss, off);
        }
        if ((hid & 63) == 0) { pw[r][wave] = s; pws[r][wave] = ss; }
    }
    __syncthreads();
    if (hid < 4) {
        float S  = pw[hid][0] + pw[hid][1] + pw[hid][2] + pw[hid][3];
        float SS = pws[hid][0] + pws[hid][1] + pws[hid][2] + pws[hid][3];
        float mu = S * (1.f / HID_);
        float var = SS * (1.f / HID_) - mu * mu;
        mu_s[hid] = mu;
        rs_s[hid] = rsqrtf(var + 1e-5f);
    }
    __syncthreads();

    float g = ln_g[hid], bb = ln_b[hid];
    float hasb = has[b];
    float psum = 0.f;
    #pragma unroll
    for (int r = 0; r < 4; ++r) {
        float outv = ((acc[r] - mu_s[r]) * rs_s[r] * g + bb) * hasb;
        seq_out[(size_t)(row0 + r) * HID_ + hid] = outv;
        psum += outv;
    }
    atomicAdd(&pooled[b * HID_ + hid], psum * (1.f / (float)Q_));
}

// ---------------------------------------------------------------------------
extern "C" void kernel_launch(void* const* d_in, const int* in_sizes, int n_in,
                              void* d_out, int out_size, void* d_ws, size_t ws_size,
                              hipStream_t stream)
{
    const float* values = (const float*)d_in[0];
    const int*   mask   = (const int*)  d_in[1];
    const float* times  = (const float*)d_in[2];
    const float* w_per  = (const float*)d_in[3];
    const float* b_per  = (const float*)d_in[4];
    const float* w_lin  = (const float*)d_in[5];
    const float* b_lin  = (const float*)d_in[6];
    const float* wq     = (const float*)d_in[7];
    const float* bq     = (const float*)d_in[8];
    const float* wk     = (const float*)d_in[9];
    const float* bk     = (const float*)d_in[10];
    const float* wo     = (const float*)d_in[11];
    const float* bo     = (const float*)d_in[12];
    const float* ln_g   = (const float*)d_in[13];
    const float* ln_b   = (const float*)d_in[14];

    float* out     = (float*)d_out;
    float* seq_out = out;                        // B*Q*HID = 262144
    float* pooled  = out + 262144;               // B*HID   = 2048
    float* qt_out  = out + 262144 + 2048;        // B*Q     = 1024

    float* ws        = (float*)d_ws;
    float*    tn      = ws;                   // 2048
    float*    has     = ws + 2048;            // 8
    float*    cm      = ws + 2056;            // 256
    float*    colmean = ws + 2312;            // 256
    float*    qproj   = ws + 2568;            // 16384
    unsigned* bitsT   = (unsigned*)(ws + 18952); // 2048 u32
    float*    mvm     = ws + 21000;           // 65536   (byte 84000, 16B-aligned)
    float*    kproj   = ws + 86536;           // 262144  (byte 346144, 16B-aligned)
    float*    ctxv    = ws + 348680;          // 262144
    float*    wot     = ws + 610824;          // 131072  -> end 741896 f32 = 2.97 MB

    kA_prep    <<<B_ + Q_ / 2,   256, 0, stream>>>(values, mask, times,
                    w_per, b_per, w_lin, b_lin, wq, bq,
                    tn, has, cm, colmean, mvm, bitsT, qproj, qt_out, pooled);
    kB_kproj_wot<<<256 + 1024,   128, 0, stream>>>(tn, w_per, b_per, w_lin, b_lin,
                    wk, bk, wo, kproj, wot);
    k3_attn    <<<dim3(Q_, B_),  256, 0, stream>>>(qproj, kproj, mvm, bitsT,
                    cm, colmean, ctxv);
    kC_gemm_ln <<<B_ * Q_ / 4,   256, 0, stream>>>(ctxv, wot, bo, cm,
                    ln_g, ln_b, has, seq_out, pooled);
}

// Round 7
// 151.499 us; speedup vs baseline: 1.8080x; 1.1635x over previous
//
#include <hip/hip_runtime.h>
#include <hip/hip_bf16.h>

// Dims (fixed by the problem)
#define B_   8
#define L_   256
#define D_   32
#define E_   128
#define H_   8
#define Q_   128
#define HID_ 256

// ---------------------------------------------------------------------------
// kA: fused prep. Blocks 0..7: per-batch prep (tn, has, mvm, bitsT, colmean,
//     cm, qt_out, pooled zero). Blocks 8..71: q-projection (2 q per block).
// block = 256 threads
// ---------------------------------------------------------------------------
__global__ __launch_bounds__(256) void kA_prep(
    const float* __restrict__ values, const int* __restrict__ mask,
    const float* __restrict__ times,
    const float* __restrict__ w_per, const float* __restrict__ b_per,
    const float* __restrict__ w_lin, const float* __restrict__ b_lin,
    const float* __restrict__ wq, const float* __restrict__ bq,
    float* __restrict__ tn, float* __restrict__ has,
    float* __restrict__ cm, float* __restrict__ colmean,
    float* __restrict__ mvm, unsigned* __restrict__ bitsT,
    float* __restrict__ qproj, float* __restrict__ qt_out,
    float* __restrict__ pooled)
{
    __shared__ float val_s[256][33];     // raw values (for colmean), padded
    __shared__ float smin[256], smax[256];
    __shared__ unsigned bits_s[256];     // [d][w] = [32][8]
    __shared__ float partial_s[8][32];
    __shared__ float sh[2];
    __shared__ __align__(16) float emb_s[2][E_];

    int blk = blockIdx.x;
    int t = threadIdx.x;

    if (blk < B_) {
        int b = blk;                       // thread t = l
        const int*   mrow = mask   + (size_t)(b * L_ + t) * D_;
        const float* vrow = values + (size_t)(b * L_ + t) * D_;
        int4  m4[8];
        float4 v4[8];
        int any = 0;
        #pragma unroll
        for (int j = 0; j < 8; ++j) {
            m4[j] = reinterpret_cast<const int4*>(mrow)[j];
            v4[j] = reinterpret_cast<const float4*>(vrow)[j];
            any |= m4[j].x | m4[j].y | m4[j].z | m4[j].w;
            float4 mv;
            mv.x = m4[j].x ? v4[j].x : 0.f;
            mv.y = m4[j].y ? v4[j].y : 0.f;
            mv.z = m4[j].z ? v4[j].z : 0.f;
            mv.w = m4[j].w ? v4[j].w : 0.f;
            reinterpret_cast<float4*>(mvm + (size_t)(b * L_ + t) * D_)[j] = mv;
            val_s[t][j * 4 + 0] = v4[j].x;
            val_s[t][j * 4 + 1] = v4[j].y;
            val_s[t][j * 4 + 2] = v4[j].z;
            val_s[t][j * 4 + 3] = v4[j].w;
        }
        // transposed mask bitmaps: bitsT[b][d][w], bit (l&63) of wave ballot
        int wave = t >> 6;
        #pragma unroll
        for (int d = 0; d < D_; ++d) {
            int comp;
            { int j = d >> 2, c = d & 3;
              int4 mm = m4[j];
              comp = (c == 0) ? mm.x : (c == 1) ? mm.y : (c == 2) ? mm.z : mm.w; }
            unsigned long long bal = __ballot(comp != 0);
            if ((t & 63) == 0) {
                bits_s[d * 8 + wave * 2 + 0] = (unsigned)(bal & 0xffffffffull);
                bits_s[d * 8 + wave * 2 + 1] = (unsigned)(bal >> 32);
            }
        }
        // time min/max over observed steps
        float tv = times[b * L_ + t];
        smin[t] = any ? tv : 1e38f;
        smax[t] = any ? tv : -1e38f;
        __syncthreads();
        for (int off = 128; off > 0; off >>= 1) {
            if (t < off) {
                smin[t] = fminf(smin[t], smin[t + off]);
                smax[t] = fmaxf(smax[t], smax[t + off]);
            }
            __syncthreads();
        }
        if (t == 0) {
            float mn = smin[0], mx = smax[0];
            float hv = (mn < 1e37f) ? 1.f : 0.f;
            sh[0] = (hv > 0.f) ? mn : 0.f;
            sh[1] = (hv > 0.f) ? mx : 1.f;
            has[b] = hv;
        }
        __syncthreads();
        float inv = 1.f / fmaxf(sh[1] - sh[0], 1e-6f);
        tn[b * L_ + t] = any ? (tv - sh[0]) * inv : 0.f;

        if (t < Q_) qt_out[b * Q_ + t] = (float)t * (1.f / 127.f);
        pooled[b * HID_ + t] = 0.f;                 // zero for kC atomics
        bitsT[b * 256 + t] = bits_s[t];

        // colmean: all 256 threads (t = lg*32 + d), then 32-thread combine
        {
            int d = t & 31, lg = t >> 5;
            float ps = 0.f;
            #pragma unroll
            for (int i = 0; i < 32; ++i) ps += val_s[lg * 32 + i][d];
            partial_s[lg][d] = ps;
        }
        __syncthreads();
        if (t < D_) {
            float s = 0.f;
            #pragma unroll
            for (int lg = 0; lg < 8; ++lg) s += partial_s[lg][t];
            colmean[b * D_ + t] = s * (1.f / (float)L_);
            unsigned o = 0;
            #pragma unroll
            for (int w = 0; w < 8; ++w) o |= bits_s[t * 8 + w];
            cm[b * D_ + t] = o ? 1.f : 0.f;
        }
    } else {
        // q-projection: 2 q per block
        int w2 = blk - B_;
        int half = t >> 7, e = t & 127;
        int q = w2 * 2 + half;
        float tt = (float)q * (1.f / 127.f);
        emb_s[half][e] = (e == 0) ? (tt * w_lin[0] + b_lin[0])
                                  : __sinf(tt * w_per[e - 1] + b_per[e - 1]);
        __syncthreads();
        const float4* wr4 = reinterpret_cast<const float4*>(wq + (size_t)e * E_);
        const float4* e4  = reinterpret_cast<const float4*>(emb_s[half]);
        float acc = bq[e];
        #pragma unroll 8
        for (int j = 0; j < E_ / 4; ++j) {
            float4 w = wr4[j], x = e4[j];
            acc += w.x * x.x + w.y * x.y + w.z * x.z + w.w * x.w;
        }
        qproj[q * E_ + e] = acc;
    }
}

// ---------------------------------------------------------------------------
// kB: k-projection, 8 rows per block, 256 threads (thread = (e, rhalf), 4
//     rows each). grid = B*L/8 = 256
// ---------------------------------------------------------------------------
__global__ __launch_bounds__(256, 4) void kB_kproj(
    const float* __restrict__ tn,
    const float* __restrict__ w_per, const float* __restrict__ b_per,
    const float* __restrict__ w_lin, const float* __restrict__ b_lin,
    const float* __restrict__ wk, const float* __restrict__ bk,
    float* __restrict__ kproj)
{
    int blk = blockIdx.x;
    int bl0 = blk * 8;
    int e = threadIdx.x & 127, rh = threadIdx.x >> 7;
    __shared__ __align__(16) float emb[8][E_];
    __shared__ float tsh[8];
    if (threadIdx.x < 8) tsh[threadIdx.x] = tn[bl0 + threadIdx.x];
    __syncthreads();
    float wp = (e == 0) ? 0.f : w_per[e - 1];
    float bp = (e == 0) ? 0.f : b_per[e - 1];
    float wl = w_lin[0], bl = b_lin[0];
    #pragma unroll
    for (int rr = 0; rr < 4; ++rr) {
        int r = rh * 4 + rr;
        float tt = tsh[r];
        emb[r][e] = (e == 0) ? (tt * wl + bl) : __sinf(tt * wp + bp);
    }
    __syncthreads();
    const float4* wr4 = reinterpret_cast<const float4*>(wk + (size_t)e * E_);
    float acc[4];
    float bias = bk[e];
    #pragma unroll
    for (int rr = 0; rr < 4; ++rr) acc[rr] = bias;
    #pragma unroll 8
    for (int j = 0; j < E_ / 4; ++j) {
        float4 w = wr4[j];
        #pragma unroll
        for (int rr = 0; rr < 4; ++rr) {
            float4 x = *reinterpret_cast<const float4*>(&emb[rh * 4 + rr][j * 4]);
            acc[rr] += w.x * x.x + w.y * x.y + w.z * x.z + w.w * x.w;
        }
    }
    #pragma unroll
    for (int rr = 0; rr < 4; ++rr)
        kproj[(size_t)(bl0 + rh * 4 + rr) * E_ + e] = acc[rr];
}

// ---------------------------------------------------------------------------
// k3: fused scores + softmax + context, LDS-resident, vectorized phase 2.
//   Phase 1 (thread=l): s[h][l] -> e_s (l-major [L][H]); per-head global max;
//                       e = exp(s - G_h).
//   Phase 2 (thread=(lseg,h,d4)): float4 accumulation over 64 l's of
//                       4 d-channels; bits in registers, two static halves.
//   Reduction over lseg via reused mvm_s region.
// grid = (Q, B), block = 256
// ---------------------------------------------------------------------------
__global__ __launch_bounds__(256, 3) void k3_attn(
    const float* __restrict__ qproj, const float* __restrict__ kproj,
    const float* __restrict__ mvm, const unsigned* __restrict__ bitsT,
    const float* __restrict__ cm, const float* __restrict__ colmean,
    float* __restrict__ ctxv)
{
    int q = blockIdx.x, b = blockIdx.y;
    int tid = threadIdx.x;
    __shared__ __align__(16) float mvm_s[L_ * D_];   // 32 KB; reused for partials
    __shared__ __align__(16) float e_s[L_ * H_];     // l-major [l][h], 8 KB
    __shared__ __align__(16) float qv_s[E_];
    __shared__ unsigned bits_s[256];
    __shared__ float gmax_s[H_];

    // stage: mvm (coalesced float4), bits, qv
    {
        const float4* src = reinterpret_cast<const float4*>(mvm + (size_t)b * L_ * D_);
        float4* dst = reinterpret_cast<float4*>(mvm_s);
        #pragma unroll
        for (int j = 0; j < 8; ++j) dst[tid + j * 256] = src[tid + j * 256];
        bits_s[tid] = bitsT[b * 256 + tid];
        if (tid < E_) qv_s[tid] = qproj[q * E_ + tid];
    }
    __syncthreads();

    // Phase 1: scores (thread = l), write raw s l-major
    const float4* kr4 = reinterpret_cast<const float4*>(kproj + (size_t)(b * L_ + tid) * E_);
    const float4* qv4 = reinterpret_cast<const float4*>(qv_s);
    float s[H_];
    #pragma unroll
    for (int h = 0; h < H_; ++h) {
        float acc = 0.f;
        #pragma unroll
        for (int j = 0; j < 4; ++j) {
            float4 kk = kr4[h * 4 + j], qq = qv4[h * 4 + j];
            acc += kk.x * qq.x + kk.y * qq.y + kk.z * qq.z + kk.w * qq.w;
        }
        s[h] = acc * 0.25f;                // 1/sqrt(EK=16)
    }
    {
        float4* er4 = reinterpret_cast<float4*>(e_s + tid * 8);
        er4[0] = *reinterpret_cast<float4*>(&s[0]);
        er4[1] = *reinterpret_cast<float4*>(&s[4]);
    }
    __syncthreads();
    // per-head global max
    {
        int h = tid >> 5, ln = tid & 31;
        float mx = -1e30f;
        #pragma unroll
        for (int j = 0; j < 8; ++j) mx = fmaxf(mx, e_s[(ln + j * 32) * 8 + h]);
        #pragma unroll
        for (int off = 16; off > 0; off >>= 1) mx = fmaxf(mx, __shfl_xor(mx, off));
        if (ln == 0) gmax_s[h] = mx;
    }
    __syncthreads();
    {
        float e8[H_];
        #pragma unroll
        for (int h = 0; h < H_; ++h) e8[h] = __expf(s[h] - gmax_s[h]);
        float4* er4 = reinterpret_cast<float4*>(e_s + tid * 8);
        er4[0] = *reinterpret_cast<float4*>(&e8[0]);
        er4[1] = *reinterpret_cast<float4*>(&e8[4]);
    }
    __syncthreads();

    // Phase 2: thread = (lseg, h, d4); 64 l's x 4 d's each
    int lseg = tid >> 6, h = (tid >> 3) & 7, d4 = tid & 7;
    unsigned w0[4], w1[4];
    #pragma unroll
    for (int j = 0; j < 4; ++j) {
        int d = d4 * 4 + j;
        w0[j] = bits_s[d * 8 + lseg * 2 + 0];
        w1[j] = bits_s[d * 8 + lseg * 2 + 1];
    }
    float4 av  = {0.f, 0.f, 0.f, 0.f};
    float4 den = {0.f, 0.f, 0.f, 0.f};
    const float4* mv4 = reinterpret_cast<const float4*>(mvm_s);
    int l0 = lseg * 64;
    #pragma unroll 8
    for (int i = 0; i < 32; ++i) {
        int l = l0 + i;
        float e = e_s[l * 8 + h];
        float4 m = mv4[l * 8 + d4];
        av.x += e * m.x; av.y += e * m.y; av.z += e * m.z; av.w += e * m.w;
        den.x += ((w0[0] >> i) & 1u) ? e : 0.f;
        den.y += ((w0[1] >> i) & 1u) ? e : 0.f;
        den.z += ((w0[2] >> i) & 1u) ? e : 0.f;
        den.w += ((w0[3] >> i) & 1u) ? e : 0.f;
    }
    #pragma unroll 8
    for (int i = 0; i < 32; ++i) {
        int l = l0 + 32 + i;
        float e = e_s[l * 8 + h];
        float4 m = mv4[l * 8 + d4];
        av.x += e * m.x; av.y += e * m.y; av.z += e * m.z; av.w += e * m.w;
        den.x += ((w1[0] >> i) & 1u) ? e : 0.f;
        den.y += ((w1[1] >> i) & 1u) ? e : 0.f;
        den.z += ((w1[2] >> i) & 1u) ? e : 0.f;
        den.w += ((w1[3] >> i) & 1u) ? e : 0.f;
    }
    __syncthreads();                       // everyone done reading mvm_s / e_s
    {
        float4* p4 = reinterpret_cast<float4*>(mvm_s);
        p4[tid * 2 + 0] = av;
        p4[tid * 2 + 1] = den;
    }
    __syncthreads();
    // final combine: thread = (h, d)
    {
        const float* part = mvm_s;
        int hh = tid >> 5, dd = tid & 31, dg = dd >> 2, jj = dd & 3;
        float a = 0.f, dn = 0.f;
        #pragma unroll
        for (int ls = 0; ls < 4; ++ls) {
            int pt = ls * 64 + hh * 8 + dg;
            a  += part[pt * 8 + jj];
            dn += part[pt * 8 + 4 + jj];
        }
        float cmf = cm[b * D_ + dd];
        float outv = (cmf > 0.f) ? (a / dn) : colmean[b * D_ + dd];
        ctxv[((size_t)(b * Q_ + q)) * 256 + hh * D_ + dd] = outv;
    }
}

// ---------------------------------------------------------------------------
// kC: output projection reading wo directly (per-lane contiguous rows).
//   Mask-channel half of the GEMM is row-independent:
//     acc_mask = sum_r cm[r] * sum_h wo[hid][h*64+32+r]  (computed once).
//   Value half: K=256 with block-uniform (scalar) A loads from ctxv.
//   + fused LayerNorm + has-mask + seq store + atomic pooled accumulation.
// grid = B*Q/4, block = HID
// ---------------------------------------------------------------------------
__global__ __launch_bounds__(256, 4) void kC_gemm_ln(
    const float* __restrict__ ctxv, const float* __restrict__ wo,
    const float* __restrict__ bo, const float* __restrict__ cm,
    const float* __restrict__ ln_g, const float* __restrict__ ln_b,
    const float* __restrict__ has,
    float* __restrict__ seq_out, float* __restrict__ pooled)
{
    int row0 = blockIdx.x * 4;              // row = b*Q + q
    int hid = threadIdx.x;
    int b = row0 >> 7;
    __shared__ float pw[4][4], pws[4][4];
    __shared__ float mu_s[4], rs_s[4];

    const float4* wrow4 = reinterpret_cast<const float4*>(wo + (size_t)hid * 512);
    const float* ar0 = ctxv + (size_t)(row0 + 0) * 256;   // block-uniform
    const float* ar1 = ctxv + (size_t)(row0 + 1) * 256;
    const float* ar2 = ctxv + (size_t)(row0 + 2) * 256;
    const float* ar3 = ctxv + (size_t)(row0 + 3) * 256;

    // cm -> 0/1 (uniform)
    float cmq[D_];
    #pragma unroll
    for (int j = 0; j < D_; ++j) cmq[j] = (cm[b * D_ + j] > 0.f) ? 1.f : 0.f;

    // mask-channel contribution (row-independent)
    float accm = 0.f;
    #pragma unroll
    for (int h1 = 0; h1 < 8; ++h1) {
        #pragma unroll
        for (int j = 0; j < 8; ++j) {
            float4 w = wrow4[h1 * 16 + 8 + j];
            accm += cmq[j * 4 + 0] * w.x + cmq[j * 4 + 1] * w.y
                  + cmq[j * 4 + 2] * w.z + cmq[j * 4 + 3] * w.w;
        }
    }

    float bias = bo[hid] + accm;
    float acc[4] = {bias, bias, bias, bias};

    // value channels: K = 256 (channel C = h1*64 + r, r<32 -> ctxv[h1*32+r])
    #pragma unroll 2
    for (int h1 = 0; h1 < 8; ++h1) {
        #pragma unroll
        for (int j = 0; j < 8; ++j) {
            float4 w = wrow4[h1 * 16 + j];
            int base = h1 * 32 + j * 4;
            acc[0] += ar0[base+0]*w.x + ar0[base+1]*w.y + ar0[base+2]*w.z + ar0[base+3]*w.w;
            acc[1] += ar1[base+0]*w.x + ar1[base+1]*w.y + ar1[base+2]*w.z + ar1[base+3]*w.w;
            acc[2] += ar2[base+0]*w.x + ar2[base+1]*w.y + ar2[base+2]*w.z + ar2[base+3]*w.w;
            acc[3] += ar3[base+0]*w.x + ar3[base+1]*w.y + ar3[base+2]*w.z + ar3[base+3]*w.w;
        }
    }

    // fused LayerNorm: per-row mean/var via wave shuffles + LDS combine
    int wave = hid >> 6;
    #pragma unroll
    for (int r = 0; r < 4; ++r) {
        float s = acc[r], ss = acc[r] * acc[r];
        #pragma unroll
        for (int off = 32; off > 0; off >>= 1) {
            s  += __shfl_xor(s, off);
            ss += __shfl_xor(ss, off);
        }
        if ((hid & 63) == 0) { pw[r][wave] = s; pws[r][wave] = ss; }
    }
    __syncthreads();
    if (hid < 4) {
        float S  = pw[hid][0] + pw[hid][1] + pw[hid][2] + pw[hid][3];
        float SS = pws[hid][0] + pws[hid][1] + pws[hid][2] + pws[hid][3];
        float mu = S * (1.f / HID_);
        float var = SS * (1.f / HID_) - mu * mu;
        mu_s[hid] = mu;
        rs_s[hid] = rsqrtf(var + 1e-5f);
    }
    __syncthreads();

    float g = ln_g[hid], bb = ln_b[hid];
    float hasb = has[b];
    float psum = 0.f;
    #pragma unroll
    for (int r = 0; r < 4; ++r) {
        float outv = ((acc[r] - mu_s[r]) * rs_s[r] * g + bb) * hasb;
        seq_out[(size_t)(row0 + r) * HID_ + hid] = outv;
        psum += outv;
    }
    atomicAdd(&pooled[b * HID_ + hid], psum * (1.f / (float)Q_));
}

// ---------------------------------------------------------------------------
extern "C" void kernel_launch(void* const* d_in, const int* in_sizes, int n_in,
                              void* d_out, int out_size, void* d_ws, size_t ws_size,
                              hipStream_t stream)
{
    const float* values = (const float*)d_in[0];
    const int*   mask   = (const int*)  d_in[1];
    const float* times  = (const float*)d_in[2];
    const float* w_per  = (const float*)d_in[3];
    const float* b_per  = (const float*)d_in[4];
    const float* w_lin  = (const float*)d_in[5];
    const float* b_lin  = (const float*)d_in[6];
    const float* wq     = (const float*)d_in[7];
    const float* bq     = (const float*)d_in[8];
    const float* wk     = (const float*)d_in[9];
    const float* bk     = (const float*)d_in[10];
    const float* wo     = (const float*)d_in[11];
    const float* bo     = (const float*)d_in[12];
    const float* ln_g   = (const float*)d_in[13];
    const float* ln_b   = (const float*)d_in[14];

    float* out     = (float*)d_out;
    float* seq_out = out;                        // B*Q*HID = 262144
    float* pooled  = out + 262144;               // B*HID   = 2048
    float* qt_out  = out + 262144 + 2048;        // B*Q     = 1024

    float* ws         = (float*)d_ws;
    float*    tn      = ws;                      // 2048
    float*    has     = ws + 2048;               // 8
    float*    cm      = ws + 2056;               // 256
    float*    colmean = ws + 2312;               // 256
    float*    qproj   = ws + 2568;               // 16384  (byte 10272, 16B-aligned)
    unsigned* bitsT   = (unsigned*)(ws + 18952); // 2048 u32
    float*    mvm     = ws + 21000;              // 65536  (byte 84000, 16B-aligned)
    float*    kproj   = ws + 86536;              // 262144 (byte 346144, 16B-aligned)
    float*    ctxv    = ws + 348680;             // 262144 -> end 610824 f32 = 2.44 MB

    kA_prep  <<<B_ + Q_ / 2,  256, 0, stream>>>(values, mask, times,
                  w_per, b_per, w_lin, b_lin, wq, bq,
                  tn, has, cm, colmean, mvm, bitsT, qproj, qt_out, pooled);
    kB_kproj <<<B_ * L_ / 8,  256, 0, stream>>>(tn, w_per, b_per, w_lin, b_lin,
                  wk, bk, kproj);
    k3_attn  <<<dim3(Q_, B_), 256, 0, stream>>>(qproj, kproj, mvm, bitsT,
                  cm, colmean, ctxv);
    kC_gemm_ln<<<B_ * Q_ / 4, 256, 0, stream>>>(ctxv, wo, bo, cm,
                  ln_g, ln_b, has, seq_out, pooled);
}

// Round 8
// 148.099 us; speedup vs baseline: 1.8496x; 1.0230x over previous
//
#include <hip/hip_runtime.h>
#include <hip/hip_bf16.h>

// Dims (fixed by the problem)
#define B_   8
#define L_   256
#define D_   32
#define E_   128
#define H_   8
#define Q_   128
#define HID_ 256

// ---------------------------------------------------------------------------
// prep1: per-batch prep. grid = B (8 blocks), block = 256 (thread = l).
//   mvm (masked values), bitsT (transposed mask bitmaps), tn, has, colmean,
//   cm, qt_out, pooled zero, and cvec[b][hid] = bo + sum_r cm[r]*wo_maskcols.
// ---------------------------------------------------------------------------
__global__ __launch_bounds__(256) void k_prep1(
    const float* __restrict__ values, const int* __restrict__ mask,
    const float* __restrict__ times,
    const float* __restrict__ wo, const float* __restrict__ bo,
    float* __restrict__ tn, float* __restrict__ has,
    float* __restrict__ cm, float* __restrict__ colmean,
    float* __restrict__ mvm, unsigned* __restrict__ bitsT,
    float* __restrict__ qt_out, float* __restrict__ pooled,
    float* __restrict__ cvec)
{
    __shared__ float val_s[256][33];     // raw values (for colmean), padded
    __shared__ float smin[256], smax[256];
    __shared__ unsigned bits_s[256];     // [d][w] = [32][8]
    __shared__ float partial_s[8][32];
    __shared__ float cm_s[D_];
    __shared__ float sh[2];

    int b = blockIdx.x;
    int t = threadIdx.x;                 // = l

    const int*   mrow = mask   + (size_t)(b * L_ + t) * D_;
    const float* vrow = values + (size_t)(b * L_ + t) * D_;
    int4  m4[8];
    float4 v4[8];
    int any = 0;
    #pragma unroll
    for (int j = 0; j < 8; ++j) {
        m4[j] = reinterpret_cast<const int4*>(mrow)[j];
        v4[j] = reinterpret_cast<const float4*>(vrow)[j];
        any |= m4[j].x | m4[j].y | m4[j].z | m4[j].w;
        float4 mv;
        mv.x = m4[j].x ? v4[j].x : 0.f;
        mv.y = m4[j].y ? v4[j].y : 0.f;
        mv.z = m4[j].z ? v4[j].z : 0.f;
        mv.w = m4[j].w ? v4[j].w : 0.f;
        reinterpret_cast<float4*>(mvm + (size_t)(b * L_ + t) * D_)[j] = mv;
        val_s[t][j * 4 + 0] = v4[j].x;
        val_s[t][j * 4 + 1] = v4[j].y;
        val_s[t][j * 4 + 2] = v4[j].z;
        val_s[t][j * 4 + 3] = v4[j].w;
    }
    // transposed mask bitmaps: bitsT[b][d][w], bit (l&63) of wave ballot
    int wave = t >> 6;
    #pragma unroll
    for (int d = 0; d < D_; ++d) {
        int comp;
        { int j = d >> 2, c = d & 3;
          int4 mm = m4[j];
          comp = (c == 0) ? mm.x : (c == 1) ? mm.y : (c == 2) ? mm.z : mm.w; }
        unsigned long long bal = __ballot(comp != 0);
        if ((t & 63) == 0) {
            bits_s[d * 8 + wave * 2 + 0] = (unsigned)(bal & 0xffffffffull);
            bits_s[d * 8 + wave * 2 + 1] = (unsigned)(bal >> 32);
        }
    }
    // time min/max over observed steps
    float tv = times[b * L_ + t];
    smin[t] = any ? tv : 1e38f;
    smax[t] = any ? tv : -1e38f;
    __syncthreads();
    for (int off = 128; off > 0; off >>= 1) {
        if (t < off) {
            smin[t] = fminf(smin[t], smin[t + off]);
            smax[t] = fmaxf(smax[t], smax[t + off]);
        }
        __syncthreads();
    }
    if (t == 0) {
        float mn = smin[0], mx = smax[0];
        float hv = (mn < 1e37f) ? 1.f : 0.f;
        sh[0] = (hv > 0.f) ? mn : 0.f;
        sh[1] = (hv > 0.f) ? mx : 1.f;
        has[b] = hv;
    }
    __syncthreads();
    float inv = 1.f / fmaxf(sh[1] - sh[0], 1e-6f);
    tn[b * L_ + t] = any ? (tv - sh[0]) * inv : 0.f;

    if (t < Q_) qt_out[b * Q_ + t] = (float)t * (1.f / 127.f);
    pooled[b * HID_ + t] = 0.f;                 // zero for k_main atomics
    bitsT[b * 256 + t] = bits_s[t];

    // colmean: all 256 threads (t = lg*32 + d), then 32-thread combine
    {
        int d = t & 31, lg = t >> 5;
        float ps = 0.f;
        #pragma unroll
        for (int i = 0; i < 32; ++i) ps += val_s[lg * 32 + i][d];
        partial_s[lg][d] = ps;
    }
    __syncthreads();
    if (t < D_) {
        float s = 0.f;
        #pragma unroll
        for (int lg = 0; lg < 8; ++lg) s += partial_s[lg][t];
        colmean[b * D_ + t] = s * (1.f / (float)L_);
        unsigned o = 0;
        #pragma unroll
        for (int w = 0; w < 8; ++w) o |= bits_s[t * 8 + w];
        float cmf = o ? 1.f : 0.f;
        cm[b * D_ + t] = cmf;
        cm_s[t] = cmf;
    }
    __syncthreads();

    // cvec[b][hid] = bo[hid] + sum_r cm[r] * wo[hid][h1*64+32+r]
    {
        int hid = t;
        const float4* wrow4 = reinterpret_cast<const float4*>(wo + (size_t)hid * 512);
        float accm = 0.f;
        #pragma unroll
        for (int h1 = 0; h1 < 8; ++h1) {
            #pragma unroll
            for (int j = 0; j < 8; ++j) {
                float4 w = wrow4[h1 * 16 + 8 + j];
                accm += cm_s[j * 4 + 0] * w.x + cm_s[j * 4 + 1] * w.y
                      + cm_s[j * 4 + 2] * w.z + cm_s[j * 4 + 3] * w.w;
            }
        }
        cvec[b * HID_ + hid] = bo[hid] + accm;
    }
}

// ---------------------------------------------------------------------------
// prep2: blocks 0..63: qproj (2 q per block). Blocks 64..319: kproj
//        (8 rows per block, thread=(e,rhalf)). Blocks 320..383: wotv
//        transpose of the VALUE channels: wotv[c][hid] = wo[hid][ (c>>5)*64 + (c&31) ].
// block = 256 threads
// ---------------------------------------------------------------------------
__global__ __launch_bounds__(256) void k_prep2(
    const float* __restrict__ tn,
    const float* __restrict__ w_per, const float* __restrict__ b_per,
    const float* __restrict__ w_lin, const float* __restrict__ b_lin,
    const float* __restrict__ wq, const float* __restrict__ bq,
    const float* __restrict__ wk, const float* __restrict__ bk,
    const float* __restrict__ wo,
    float* __restrict__ qproj, float* __restrict__ kproj,
    float* __restrict__ wotv)
{
    __shared__ __align__(16) float emb_q[2][E_];
    __shared__ __align__(16) float emb_k[8][E_];
    __shared__ float tsh[8];

    int blk = blockIdx.x;
    int t = threadIdx.x;

    if (blk < 64) {
        // q-projection: 2 q per block
        int half = t >> 7, e = t & 127;
        int q = blk * 2 + half;
        float tt = (float)q * (1.f / 127.f);
        emb_q[half][e] = (e == 0) ? (tt * w_lin[0] + b_lin[0])
                                  : __sinf(tt * w_per[e - 1] + b_per[e - 1]);
        __syncthreads();
        const float4* wr4 = reinterpret_cast<const float4*>(wq + (size_t)e * E_);
        const float4* e4  = reinterpret_cast<const float4*>(emb_q[half]);
        float acc = bq[e];
        #pragma unroll 8
        for (int j = 0; j < E_ / 4; ++j) {
            float4 w = wr4[j], x = e4[j];
            acc += w.x * x.x + w.y * x.y + w.z * x.z + w.w * x.w;
        }
        qproj[q * E_ + e] = acc;
    } else if (blk < 320) {
        // k-projection: 8 rows per block, 4 rows per thread-half
        int bl0 = (blk - 64) * 8;
        int e = t & 127, rh = t >> 7;
        if (t < 8) tsh[t] = tn[bl0 + t];
        __syncthreads();
        float wp = (e == 0) ? 0.f : w_per[e - 1];
        float bp = (e == 0) ? 0.f : b_per[e - 1];
        float wl = w_lin[0], bl = b_lin[0];
        #pragma unroll
        for (int rr = 0; rr < 4; ++rr) {
            int r = rh * 4 + rr;
            float tt = tsh[r];
            emb_k[r][e] = (e == 0) ? (tt * wl + bl) : __sinf(tt * wp + bp);
        }
        __syncthreads();
        const float4* wr4 = reinterpret_cast<const float4*>(wk + (size_t)e * E_);
        float bias = bk[e];
        float acc[4] = {bias, bias, bias, bias};
        #pragma unroll 8
        for (int j = 0; j < E_ / 4; ++j) {
            float4 w = wr4[j];
            #pragma unroll
            for (int rr = 0; rr < 4; ++rr) {
                float4 x = *reinterpret_cast<const float4*>(&emb_k[rh * 4 + rr][j * 4]);
                acc[rr] += w.x * x.x + w.y * x.y + w.z * x.z + w.w * x.w;
            }
        }
        #pragma unroll
        for (int rr = 0; rr < 4; ++rr)
            kproj[(size_t)(bl0 + rh * 4 + rr) * E_ + e] = acc[rr];
    } else {
        // wotv transpose (value channels only), 4 c per block
        int c0 = (blk - 320) * 4;
        #pragma unroll
        for (int j = 0; j < 4; ++j) {
            int c = c0 + j;
            int col = (c >> 5) * 64 + (c & 31);
            wotv[(size_t)c * HID_ + t] = wo[(size_t)t * 512 + col];
        }
    }
}

// ---------------------------------------------------------------------------
// k_main: fused scores + softmax + context + output GEMM + LayerNorm + pool.
//   Phase 1 (thread=l): s[h][l] -> e_s (l-major [L][H]); per-head global max;
//                       e = exp(s - G_h).
//   Phase 2 (thread=(lseg,h,d4)): float4 accumulation over 64 l's of 4 d's;
//                       bits in registers; partials via reused mvm_s.
//   Combine -> ctx_s[256] (LDS).
//   GEMM (thread=hid): acc = cvec[b][hid] + sum_c ctx_s[c]*wotv[c][hid]
//   LN (biased var, eps 1e-5) * has -> seq row; atomicAdd pooled/Q.
// grid = (Q, B), block = 256
// ---------------------------------------------------------------------------
__global__ __launch_bounds__(256, 3) void k_main(
    const float* __restrict__ qproj, const float* __restrict__ kproj,
    const float* __restrict__ mvm, const unsigned* __restrict__ bitsT,
    const float* __restrict__ cm, const float* __restrict__ colmean,
    const float* __restrict__ wotv, const float* __restrict__ cvec,
    const float* __restrict__ has,
    const float* __restrict__ ln_g, const float* __restrict__ ln_b,
    float* __restrict__ seq_out, float* __restrict__ pooled)
{
    int q = blockIdx.x, b = blockIdx.y;
    int tid = threadIdx.x;
    __shared__ __align__(16) float mvm_s[L_ * D_];   // 32 KB; reused for partials
    __shared__ __align__(16) float e_s[L_ * H_];     // l-major [l][h], 8 KB
    __shared__ __align__(16) float qv_s[E_];
    __shared__ unsigned bits_s[256];
    __shared__ float gmax_s[H_];
    __shared__ __align__(16) float ctx_s[256];
    __shared__ float red_s[8];
    __shared__ float mu_rs[2];

    // stage: mvm (coalesced float4), bits, qv
    {
        const float4* src = reinterpret_cast<const float4*>(mvm + (size_t)b * L_ * D_);
        float4* dst = reinterpret_cast<float4*>(mvm_s);
        #pragma unroll
        for (int j = 0; j < 8; ++j) dst[tid + j * 256] = src[tid + j * 256];
        bits_s[tid] = bitsT[b * 256 + tid];
        if (tid < E_) qv_s[tid] = qproj[q * E_ + tid];
    }
    __syncthreads();

    // Phase 1: scores (thread = l), write raw s l-major
    const float4* kr4 = reinterpret_cast<const float4*>(kproj + (size_t)(b * L_ + tid) * E_);
    const float4* qv4 = reinterpret_cast<const float4*>(qv_s);
    float s[H_];
    #pragma unroll
    for (int h = 0; h < H_; ++h) {
        float acc = 0.f;
        #pragma unroll
        for (int j = 0; j < 4; ++j) {
            float4 kk = kr4[h * 4 + j], qq = qv4[h * 4 + j];
            acc += kk.x * qq.x + kk.y * qq.y + kk.z * qq.z + kk.w * qq.w;
        }
        s[h] = acc * 0.25f;                // 1/sqrt(EK=16)
    }
    {
        float4* er4 = reinterpret_cast<float4*>(e_s + tid * 8);
        er4[0] = *reinterpret_cast<float4*>(&s[0]);
        er4[1] = *reinterpret_cast<float4*>(&s[4]);
    }
    __syncthreads();
    // per-head global max
    {
        int h = tid >> 5, ln = tid & 31;
        float mx = -1e30f;
        #pragma unroll
        for (int j = 0; j < 8; ++j) mx = fmaxf(mx, e_s[(ln + j * 32) * 8 + h]);
        #pragma unroll
        for (int off = 16; off > 0; off >>= 1) mx = fmaxf(mx, __shfl_xor(mx, off));
        if (ln == 0) gmax_s[h] = mx;
    }
    __syncthreads();
    {
        float e8[H_];
        #pragma unroll
        for (int h = 0; h < H_; ++h) e8[h] = __expf(s[h] - gmax_s[h]);
        float4* er4 = reinterpret_cast<float4*>(e_s + tid * 8);
        er4[0] = *reinterpret_cast<float4*>(&e8[0]);
        er4[1] = *reinterpret_cast<float4*>(&e8[4]);
    }
    __syncthreads();

    // Phase 2: thread = (lseg, h, d4); 64 l's x 4 d's each
    {
        int lseg = tid >> 6, h = (tid >> 3) & 7, d4 = tid & 7;
        unsigned w0[4], w1[4];
        #pragma unroll
        for (int j = 0; j < 4; ++j) {
            int d = d4 * 4 + j;
            w0[j] = bits_s[d * 8 + lseg * 2 + 0];
            w1[j] = bits_s[d * 8 + lseg * 2 + 1];
        }
        float4 av  = {0.f, 0.f, 0.f, 0.f};
        float4 den = {0.f, 0.f, 0.f, 0.f};
        const float4* mv4 = reinterpret_cast<const float4*>(mvm_s);
        int l0 = lseg * 64;
        #pragma unroll 8
        for (int i = 0; i < 32; ++i) {
            int l = l0 + i;
            float e = e_s[l * 8 + h];
            float4 m = mv4[l * 8 + d4];
            av.x += e * m.x; av.y += e * m.y; av.z += e * m.z; av.w += e * m.w;
            den.x += ((w0[0] >> i) & 1u) ? e : 0.f;
            den.y += ((w0[1] >> i) & 1u) ? e : 0.f;
            den.z += ((w0[2] >> i) & 1u) ? e : 0.f;
            den.w += ((w0[3] >> i) & 1u) ? e : 0.f;
        }
        #pragma unroll 8
        for (int i = 0; i < 32; ++i) {
            int l = l0 + 32 + i;
            float e = e_s[l * 8 + h];
            float4 m = mv4[l * 8 + d4];
            av.x += e * m.x; av.y += e * m.y; av.z += e * m.z; av.w += e * m.w;
            den.x += ((w1[0] >> i) & 1u) ? e : 0.f;
            den.y += ((w1[1] >> i) & 1u) ? e : 0.f;
            den.z += ((w1[2] >> i) & 1u) ? e : 0.f;
            den.w += ((w1[3] >> i) & 1u) ? e : 0.f;
        }
        __syncthreads();                 // everyone done reading mvm_s / e_s
        float4* p4 = reinterpret_cast<float4*>(mvm_s);
        p4[tid * 2 + 0] = av;
        p4[tid * 2 + 1] = den;
    }
    __syncthreads();
    // combine: thread tid = (hh, dd) writes ctx_s[tid]
    {
        const float* part = mvm_s;
        int hh = tid >> 5, dd = tid & 31, dg = dd >> 2, jj = dd & 3;
        float a = 0.f, dn = 0.f;
        #pragma unroll
        for (int ls = 0; ls < 4; ++ls) {
            int pt = ls * 64 + hh * 8 + dg;
            a  += part[pt * 8 + jj];
            dn += part[pt * 8 + 4 + jj];
        }
        float cmf = cm[b * D_ + dd];
        ctx_s[tid] = (cmf > 0.f) ? (a / dn) : colmean[b * D_ + dd];
    }
    __syncthreads();

    // GEMM: thread = hid; K = 256 value channels (coalesced wotv loads,
    // broadcast ctx_s reads)
    int hid = tid;
    float acc = cvec[b * HID_ + hid];
    #pragma unroll 4
    for (int c4 = 0; c4 < 64; ++c4) {
        float w0 = wotv[(size_t)(c4 * 4 + 0) * HID_ + hid];
        float w1 = wotv[(size_t)(c4 * 4 + 1) * HID_ + hid];
        float w2 = wotv[(size_t)(c4 * 4 + 2) * HID_ + hid];
        float w3 = wotv[(size_t)(c4 * 4 + 3) * HID_ + hid];
        float4 cx = *reinterpret_cast<const float4*>(&ctx_s[c4 * 4]);
        acc += cx.x * w0 + cx.y * w1 + cx.z * w2 + cx.w * w3;
    }

    // fused LayerNorm (single row)
    int wave = hid >> 6;
    {
        float sum = acc, ssum = acc * acc;
        #pragma unroll
        for (int off = 32; off > 0; off >>= 1) {
            sum  += __shfl_xor(sum, off);
            ssum += __shfl_xor(ssum, off);
        }
        if ((hid & 63) == 0) { red_s[wave] = sum; red_s[4 + wave] = ssum; }
    }
    __syncthreads();
    if (hid == 0) {
        float S  = red_s[0] + red_s[1] + red_s[2] + red_s[3];
        float SS = red_s[4] + red_s[5] + red_s[6] + red_s[7];
        float mu = S * (1.f / HID_);
        float var = SS * (1.f / HID_) - mu * mu;
        mu_rs[0] = mu;
        mu_rs[1] = rsqrtf(var + 1e-5f);
    }
    __syncthreads();

    float outv = ((acc - mu_rs[0]) * mu_rs[1] * ln_g[hid] + ln_b[hid]) * has[b];
    seq_out[((size_t)(b * Q_ + q)) * HID_ + hid] = outv;
    atomicAdd(&pooled[b * HID_ + hid], outv * (1.f / (float)Q_));
}

// ---------------------------------------------------------------------------
extern "C" void kernel_launch(void* const* d_in, const int* in_sizes, int n_in,
                              void* d_out, int out_size, void* d_ws, size_t ws_size,
                              hipStream_t stream)
{
    const float* values = (const float*)d_in[0];
    const int*   mask   = (const int*)  d_in[1];
    const float* times  = (const float*)d_in[2];
    const float* w_per  = (const float*)d_in[3];
    const float* b_per  = (const float*)d_in[4];
    const float* w_lin  = (const float*)d_in[5];
    const float* b_lin  = (const float*)d_in[6];
    const float* wq     = (const float*)d_in[7];
    const float* bq     = (const float*)d_in[8];
    const float* wk     = (const float*)d_in[9];
    const float* bk     = (const float*)d_in[10];
    const float* wo     = (const float*)d_in[11];
    const float* bo     = (const float*)d_in[12];
    const float* ln_g   = (const float*)d_in[13];
    const float* ln_b   = (const float*)d_in[14];

    float* out     = (float*)d_out;
    float* seq_out = out;                        // B*Q*HID = 262144
    float* pooled  = out + 262144;               // B*HID   = 2048
    float* qt_out  = out + 262144 + 2048;        // B*Q     = 1024

    float* ws         = (float*)d_ws;
    float*    tn      = ws;                      // 2048
    float*    has     = ws + 2048;               // 8
    float*    cm      = ws + 2056;               // 256
    float*    colmean = ws + 2312;               // 256
    float*    qproj   = ws + 2568;               // 16384  (byte 10272, 16B-aligned)
    unsigned* bitsT   = (unsigned*)(ws + 18952); // 2048 u32
    float*    mvm     = ws + 21000;              // 65536  (byte 84000, 16B-aligned)
    float*    kproj   = ws + 86536;              // 262144 (byte 346144, 16B-aligned)
    float*    cvec    = ws + 348680;             // 2048
    float*    wotv    = ws + 350728;             // 65536 -> end 416264 f32 = 1.67 MB

    k_prep1<<<B_,            256, 0, stream>>>(values, mask, times, wo, bo,
                 tn, has, cm, colmean, mvm, bitsT, qt_out, pooled, cvec);
    k_prep2<<<384,           256, 0, stream>>>(tn, w_per, b_per, w_lin, b_lin,
                 wq, bq, wk, bk, wo, qproj, kproj, wotv);
    k_main <<<dim3(Q_, B_),  256, 0, stream>>>(qproj, kproj, mvm, bitsT,
                 cm, colmean, wotv, cvec, has, ln_g, ln_b, seq_out, pooled);
}

// Round 9
// 133.626 us; speedup vs baseline: 2.0499x; 1.1083x over previous
//
#include <hip/hip_runtime.h>
#include <hip/hip_bf16.h>

// Dims (fixed by the problem)
#define B_   8
#define L_   256
#define D_   32
#define E_   128
#define H_   8
#define Q_   128
#define HID_ 256

// ---------------------------------------------------------------------------
// prep1: per-batch prep. grid = B (8 blocks), block = 256 (thread = l).
//   mvm (masked values), bitsT (transposed mask bitmaps), tn, has, colmean,
//   cm, qt_out, pooled zero. (cvec moved to prep2.)
// ---------------------------------------------------------------------------
__global__ __launch_bounds__(256) void k_prep1(
    const float* __restrict__ values, const int* __restrict__ mask,
    const float* __restrict__ times,
    float* __restrict__ tn, float* __restrict__ has,
    float* __restrict__ cm, float* __restrict__ colmean,
    float* __restrict__ mvm, unsigned* __restrict__ bitsT,
    float* __restrict__ qt_out, float* __restrict__ pooled)
{
    __shared__ float val_s[256][33];     // raw values (for colmean), padded
    __shared__ unsigned bits_s[256];     // [d][w] = [32][8]
    __shared__ float partial_s[8][32];
    __shared__ float sminw[4], smaxw[4];
    __shared__ float sh[2];

    int b = blockIdx.x;
    int t = threadIdx.x;                 // = l

    const int*   mrow = mask   + (size_t)(b * L_ + t) * D_;
    const float* vrow = values + (size_t)(b * L_ + t) * D_;
    int4  m4[8];
    float4 v4[8];
    int any = 0;
    #pragma unroll
    for (int j = 0; j < 8; ++j) {
        m4[j] = reinterpret_cast<const int4*>(mrow)[j];
        v4[j] = reinterpret_cast<const float4*>(vrow)[j];
        any |= m4[j].x | m4[j].y | m4[j].z | m4[j].w;
        float4 mv;
        mv.x = m4[j].x ? v4[j].x : 0.f;
        mv.y = m4[j].y ? v4[j].y : 0.f;
        mv.z = m4[j].z ? v4[j].z : 0.f;
        mv.w = m4[j].w ? v4[j].w : 0.f;
        reinterpret_cast<float4*>(mvm + (size_t)(b * L_ + t) * D_)[j] = mv;
        val_s[t][j * 4 + 0] = v4[j].x;
        val_s[t][j * 4 + 1] = v4[j].y;
        val_s[t][j * 4 + 2] = v4[j].z;
        val_s[t][j * 4 + 3] = v4[j].w;
    }
    // transposed mask bitmaps: bitsT[b][d][w], bit (l&63) of wave ballot
    int wave = t >> 6;
    #pragma unroll
    for (int d = 0; d < D_; ++d) {
        int comp;
        { int j = d >> 2, c = d & 3;
          int4 mm = m4[j];
          comp = (c == 0) ? mm.x : (c == 1) ? mm.y : (c == 2) ? mm.z : mm.w; }
        unsigned long long bal = __ballot(comp != 0);
        if ((t & 63) == 0) {
            bits_s[d * 8 + wave * 2 + 0] = (unsigned)(bal & 0xffffffffull);
            bits_s[d * 8 + wave * 2 + 1] = (unsigned)(bal >> 32);
        }
    }
    // time min/max over observed steps: wave shfl reduce + tiny combine
    float tv = times[b * L_ + t];
    {
        float wmin = any ? tv : 1e38f;
        float wmax = any ? tv : -1e38f;
        #pragma unroll
        for (int off = 32; off > 0; off >>= 1) {
            wmin = fminf(wmin, __shfl_xor(wmin, off));
            wmax = fmaxf(wmax, __shfl_xor(wmax, off));
        }
        if ((t & 63) == 0) { sminw[wave] = wmin; smaxw[wave] = wmax; }
    }
    // colmean partials (independent of min/max)
    {
        int d = t & 31, lg = t >> 5;
        float ps = 0.f;
        #pragma unroll
        for (int i = 0; i < 32; ++i) ps += val_s[lg * 32 + i][d];
        partial_s[lg][d] = ps;
    }
    __syncthreads();
    if (t == 0) {
        float mn = fminf(fminf(sminw[0], sminw[1]), fminf(sminw[2], sminw[3]));
        float mx = fmaxf(fmaxf(smaxw[0], smaxw[1]), fmaxf(smaxw[2], smaxw[3]));
        float hv = (mn < 1e37f) ? 1.f : 0.f;
        sh[0] = (hv > 0.f) ? mn : 0.f;
        sh[1] = (hv > 0.f) ? mx : 1.f;
        has[b] = hv;
    }
    __syncthreads();
    float inv = 1.f / fmaxf(sh[1] - sh[0], 1e-6f);
    tn[b * L_ + t] = any ? (tv - sh[0]) * inv : 0.f;

    if (t < Q_) qt_out[b * Q_ + t] = (float)t * (1.f / 127.f);
    pooled[b * HID_ + t] = 0.f;                 // zero for k_main atomics
    bitsT[b * 256 + t] = bits_s[t];

    if (t < D_) {
        float s = 0.f;
        #pragma unroll
        for (int lg = 0; lg < 8; ++lg) s += partial_s[lg][t];
        colmean[b * D_ + t] = s * (1.f / (float)L_);
        unsigned o = 0;
        #pragma unroll
        for (int w = 0; w < 8; ++w) o |= bits_s[t * 8 + w];
        cm[b * D_ + t] = o ? 1.f : 0.f;
    }
}

// ---------------------------------------------------------------------------
// prep2: blocks 0..63: qproj (2 q/block). 64..319: kproj (8 rows/block).
//        320..383: wotv transpose (value channels). 384..391: cvec per batch.
// block = 256 threads
// ---------------------------------------------------------------------------
__global__ __launch_bounds__(256) void k_prep2(
    const float* __restrict__ tn, const float* __restrict__ cm,
    const float* __restrict__ w_per, const float* __restrict__ b_per,
    const float* __restrict__ w_lin, const float* __restrict__ b_lin,
    const float* __restrict__ wq, const float* __restrict__ bq,
    const float* __restrict__ wk, const float* __restrict__ bk,
    const float* __restrict__ wo, const float* __restrict__ bo,
    float* __restrict__ qproj, float* __restrict__ kproj,
    float* __restrict__ wotv, float* __restrict__ cvec)
{
    __shared__ __align__(16) float emb_q[2][E_];
    __shared__ __align__(16) float emb_k[8][E_];
    __shared__ float tsh[8];
    __shared__ float cm_s[D_];

    int blk = blockIdx.x;
    int t = threadIdx.x;

    if (blk < 64) {
        // q-projection: 2 q per block
        int half = t >> 7, e = t & 127;
        int q = blk * 2 + half;
        float tt = (float)q * (1.f / 127.f);
        emb_q[half][e] = (e == 0) ? (tt * w_lin[0] + b_lin[0])
                                  : __sinf(tt * w_per[e - 1] + b_per[e - 1]);
        __syncthreads();
        const float4* wr4 = reinterpret_cast<const float4*>(wq + (size_t)e * E_);
        const float4* e4  = reinterpret_cast<const float4*>(emb_q[half]);
        float acc = bq[e];
        #pragma unroll 8
        for (int j = 0; j < E_ / 4; ++j) {
            float4 w = wr4[j], x = e4[j];
            acc += w.x * x.x + w.y * x.y + w.z * x.z + w.w * x.w;
        }
        qproj[q * E_ + e] = acc;
    } else if (blk < 320) {
        // k-projection: 8 rows per block, 4 rows per thread-half
        int bl0 = (blk - 64) * 8;
        int e = t & 127, rh = t >> 7;
        if (t < 8) tsh[t] = tn[bl0 + t];
        __syncthreads();
        float wp = (e == 0) ? 0.f : w_per[e - 1];
        float bp = (e == 0) ? 0.f : b_per[e - 1];
        float wl = w_lin[0], bl = b_lin[0];
        #pragma unroll
        for (int rr = 0; rr < 4; ++rr) {
            int r = rh * 4 + rr;
            float tt = tsh[r];
            emb_k[r][e] = (e == 0) ? (tt * wl + bl) : __sinf(tt * wp + bp);
        }
        __syncthreads();
        const float4* wr4 = reinterpret_cast<const float4*>(wk + (size_t)e * E_);
        float bias = bk[e];
        float acc[4] = {bias, bias, bias, bias};
        #pragma unroll 8
        for (int j = 0; j < E_ / 4; ++j) {
            float4 w = wr4[j];
            #pragma unroll
            for (int rr = 0; rr < 4; ++rr) {
                float4 x = *reinterpret_cast<const float4*>(&emb_k[rh * 4 + rr][j * 4]);
                acc[rr] += w.x * x.x + w.y * x.y + w.z * x.z + w.w * x.w;
            }
        }
        #pragma unroll
        for (int rr = 0; rr < 4; ++rr)
            kproj[(size_t)(bl0 + rh * 4 + rr) * E_ + e] = acc[rr];
    } else if (blk < 384) {
        // wotv transpose (value channels only), 4 c per block
        int c0 = (blk - 320) * 4;
        #pragma unroll
        for (int j = 0; j < 4; ++j) {
            int c = c0 + j;
            int col = (c >> 5) * 64 + (c & 31);
            wotv[(size_t)c * HID_ + t] = wo[(size_t)t * 512 + col];
        }
    } else {
        // cvec[b][hid] = bo[hid] + sum_r cm[b][r] * wo[hid][h1*64+32+r]
        int b = blk - 384;
        if (t < D_) cm_s[t] = cm[b * D_ + t];
        __syncthreads();
        int hid = t;
        const float4* wrow4 = reinterpret_cast<const float4*>(wo + (size_t)hid * 512);
        float accm = 0.f;
        #pragma unroll
        for (int h1 = 0; h1 < 8; ++h1) {
            #pragma unroll
            for (int j = 0; j < 8; ++j) {
                float4 w = wrow4[h1 * 16 + 8 + j];
                accm += cm_s[j * 4 + 0] * w.x + cm_s[j * 4 + 1] * w.y
                      + cm_s[j * 4 + 2] * w.z + cm_s[j * 4 + 3] * w.w;
            }
        }
        cvec[b * HID_ + hid] = bo[hid] + accm;
    }
}

// ---------------------------------------------------------------------------
// k_main: fused scores + softmax + context + output GEMM + LN + pool,
//         TWO q rows per block (amortizes staging, barriers, wotv stream).
// grid = (Q/2, B), block = 256
// ---------------------------------------------------------------------------
__global__ __launch_bounds__(256, 3) void k_main(
    const float* __restrict__ qproj, const float* __restrict__ kproj,
    const float* __restrict__ mvm, const unsigned* __restrict__ bitsT,
    const float* __restrict__ cm, const float* __restrict__ colmean,
    const float* __restrict__ wotv, const float* __restrict__ cvec,
    const float* __restrict__ has,
    const float* __restrict__ ln_g, const float* __restrict__ ln_b,
    float* __restrict__ seq_out, float* __restrict__ pooled)
{
    int qb = blockIdx.x, b = blockIdx.y;
    int tid = threadIdx.x;
    __shared__ __align__(16) float mvm_s[L_ * D_];   // 32 KB; reused for partials
    __shared__ __align__(16) float e_s[2][L_ * H_];  // l-major [l][h], 16 KB
    __shared__ __align__(16) float qv_s[2][E_];
    __shared__ unsigned bits_s[256];
    __shared__ float gmax_s[16];
    __shared__ __align__(16) float ctx_s[2][256];
    __shared__ float red_s[2][8];
    __shared__ float mu_rs[2][2];

    // stage: mvm (coalesced float4), bits, qv for both q
    {
        const float4* src = reinterpret_cast<const float4*>(mvm + (size_t)b * L_ * D_);
        float4* dst = reinterpret_cast<float4*>(mvm_s);
        #pragma unroll
        for (int j = 0; j < 8; ++j) dst[tid + j * 256] = src[tid + j * 256];
        bits_s[tid] = bitsT[b * 256 + tid];
        int half = tid >> 7, e = tid & 127;
        qv_s[half][e] = qproj[(qb * 2 + half) * E_ + e];
    }
    __syncthreads();

    // Phase 1: scores for both q (thread = l), raw s l-major
    const float4* kr4 = reinterpret_cast<const float4*>(kproj + (size_t)(b * L_ + tid) * E_);
    const float4* q04 = reinterpret_cast<const float4*>(qv_s[0]);
    const float4* q14 = reinterpret_cast<const float4*>(qv_s[1]);
    float s0[H_], s1[H_];
    #pragma unroll
    for (int h = 0; h < H_; ++h) {
        float a0 = 0.f, a1 = 0.f;
        #pragma unroll
        for (int j = 0; j < 4; ++j) {
            float4 kk = kr4[h * 4 + j];
            float4 qa = q04[h * 4 + j], qb4 = q14[h * 4 + j];
            a0 += kk.x * qa.x + kk.y * qa.y + kk.z * qa.z + kk.w * qa.w;
            a1 += kk.x * qb4.x + kk.y * qb4.y + kk.z * qb4.z + kk.w * qb4.w;
        }
        s0[h] = a0 * 0.25f;                // 1/sqrt(EK=16)
        s1[h] = a1 * 0.25f;
    }
    {
        float4* e04 = reinterpret_cast<float4*>(&e_s[0][tid * 8]);
        float4* e14 = reinterpret_cast<float4*>(&e_s[1][tid * 8]);
        e04[0] = *reinterpret_cast<float4*>(&s0[0]);
        e04[1] = *reinterpret_cast<float4*>(&s0[4]);
        e14[0] = *reinterpret_cast<float4*>(&s1[0]);
        e14[1] = *reinterpret_cast<float4*>(&s1[4]);
    }
    __syncthreads();
    // per-(q,h) global max: 16 groups of 16 lanes
    {
        int g = tid >> 4, ln = tid & 15;
        int qi = g >> 3, h = g & 7;
        float mx = -1e30f;
        #pragma unroll
        for (int j = 0; j < 16; ++j) mx = fmaxf(mx, e_s[qi][(ln + j * 16) * 8 + h]);
        #pragma unroll
        for (int off = 8; off > 0; off >>= 1) mx = fmaxf(mx, __shfl_xor(mx, off));
        if (ln == 0) gmax_s[g] = mx;
    }
    __syncthreads();
    {
        float e0[H_], e1[H_];
        #pragma unroll
        for (int h = 0; h < H_; ++h) {
            e0[h] = __expf(s0[h] - gmax_s[h]);
            e1[h] = __expf(s1[h] - gmax_s[8 + h]);
        }
        float4* e04 = reinterpret_cast<float4*>(&e_s[0][tid * 8]);
        float4* e14 = reinterpret_cast<float4*>(&e_s[1][tid * 8]);
        e04[0] = *reinterpret_cast<float4*>(&e0[0]);
        e04[1] = *reinterpret_cast<float4*>(&e0[4]);
        e14[0] = *reinterpret_cast<float4*>(&e1[0]);
        e14[1] = *reinterpret_cast<float4*>(&e1[4]);
    }
    __syncthreads();

    // Phase 2: thread = (lseg, h, d4); 64 l's x 4 d's, both q at once
    {
        int lseg = tid >> 6, h = (tid >> 3) & 7, d4 = tid & 7;
        unsigned w0[4], w1[4];
        #pragma unroll
        for (int j = 0; j < 4; ++j) {
            int d = d4 * 4 + j;
            w0[j] = bits_s[d * 8 + lseg * 2 + 0];
            w1[j] = bits_s[d * 8 + lseg * 2 + 1];
        }
        float4 av0 = {0,0,0,0}, dn0 = {0,0,0,0};
        float4 av1 = {0,0,0,0}, dn1 = {0,0,0,0};
        const float4* mv4 = reinterpret_cast<const float4*>(mvm_s);
        const float* e0p = e_s[0];
        const float* e1p = e_s[1];
        int l0 = lseg * 64;
        #pragma unroll 8
        for (int i = 0; i < 32; ++i) {
            int l = l0 + i;
            float ea = e0p[l * 8 + h], eb = e1p[l * 8 + h];
            float4 m = mv4[l * 8 + d4];
            av0.x += ea * m.x; av0.y += ea * m.y; av0.z += ea * m.z; av0.w += ea * m.w;
            av1.x += eb * m.x; av1.y += eb * m.y; av1.z += eb * m.z; av1.w += eb * m.w;
            bool b0 = (w0[0] >> i) & 1u, b1 = (w0[1] >> i) & 1u;
            bool b2 = (w0[2] >> i) & 1u, b3 = (w0[3] >> i) & 1u;
            dn0.x += b0 ? ea : 0.f; dn1.x += b0 ? eb : 0.f;
            dn0.y += b1 ? ea : 0.f; dn1.y += b1 ? eb : 0.f;
            dn0.z += b2 ? ea : 0.f; dn1.z += b2 ? eb : 0.f;
            dn0.w += b3 ? ea : 0.f; dn1.w += b3 ? eb : 0.f;
        }
        #pragma unroll 8
        for (int i = 0; i < 32; ++i) {
            int l = l0 + 32 + i;
            float ea = e0p[l * 8 + h], eb = e1p[l * 8 + h];
            float4 m = mv4[l * 8 + d4];
            av0.x += ea * m.x; av0.y += ea * m.y; av0.z += ea * m.z; av0.w += ea * m.w;
            av1.x += eb * m.x; av1.y += eb * m.y; av1.z += eb * m.z; av1.w += eb * m.w;
            bool b0 = (w1[0] >> i) & 1u, b1 = (w1[1] >> i) & 1u;
            bool b2 = (w1[2] >> i) & 1u, b3 = (w1[3] >> i) & 1u;
            dn0.x += b0 ? ea : 0.f; dn1.x += b0 ? eb : 0.f;
            dn0.y += b1 ? ea : 0.f; dn1.y += b1 ? eb : 0.f;
            dn0.z += b2 ? ea : 0.f; dn1.z += b2 ? eb : 0.f;
            dn0.w += b3 ? ea : 0.f; dn1.w += b3 ? eb : 0.f;
        }
        __syncthreads();                 // everyone done reading mvm_s / e_s
        float4* p4 = reinterpret_cast<float4*>(mvm_s);
        p4[tid * 4 + 0] = av0;
        p4[tid * 4 + 1] = dn0;
        p4[tid * 4 + 2] = av1;
        p4[tid * 4 + 3] = dn1;
    }
    __syncthreads();
    // combine: thread tid = (hh, dd) writes ctx_s[qi][tid]
    {
        int hh = tid >> 5, dd = tid & 31, dg = dd >> 2, jj = dd & 3;
        float a0 = 0.f, d0 = 0.f, a1 = 0.f, d1 = 0.f;
        #pragma unroll
        for (int ls = 0; ls < 4; ++ls) {
            int pt = ls * 64 + hh * 8 + dg;
            a0 += mvm_s[pt * 16 + jj];
            d0 += mvm_s[pt * 16 + 4 + jj];
            a1 += mvm_s[pt * 16 + 8 + jj];
            d1 += mvm_s[pt * 16 + 12 + jj];
        }
        float cmf = cm[b * D_ + dd];
        float cmn = colmean[b * D_ + dd];
        ctx_s[0][tid] = (cmf > 0.f) ? (a0 / d0) : cmn;
        ctx_s[1][tid] = (cmf > 0.f) ? (a1 / d1) : cmn;
    }
    __syncthreads();

    // GEMM: thread = hid; K = 256 value channels; wotv stream serves both q
    int hid = tid;
    float cv = cvec[b * HID_ + hid];
    float acc0 = cv, acc1 = cv;
    #pragma unroll 4
    for (int c4 = 0; c4 < 64; ++c4) {
        float w0 = wotv[(size_t)(c4 * 4 + 0) * HID_ + hid];
        float w1 = wotv[(size_t)(c4 * 4 + 1) * HID_ + hid];
        float w2 = wotv[(size_t)(c4 * 4 + 2) * HID_ + hid];
        float w3 = wotv[(size_t)(c4 * 4 + 3) * HID_ + hid];
        float4 c0 = *reinterpret_cast<const float4*>(&ctx_s[0][c4 * 4]);
        float4 c1 = *reinterpret_cast<const float4*>(&ctx_s[1][c4 * 4]);
        acc0 += c0.x * w0 + c0.y * w1 + c0.z * w2 + c0.w * w3;
        acc1 += c1.x * w0 + c1.y * w1 + c1.z * w2 + c1.w * w3;
    }

    // fused LayerNorm for both rows
    int wave = hid >> 6;
    {
        float su0 = acc0, ss0 = acc0 * acc0;
        float su1 = acc1, ss1 = acc1 * acc1;
        #pragma unroll
        for (int off = 32; off > 0; off >>= 1) {
            su0 += __shfl_xor(su0, off);
            ss0 += __shfl_xor(ss0, off);
            su1 += __shfl_xor(su1, off);
            ss1 += __shfl_xor(ss1, off);
        }
        if ((hid & 63) == 0) {
            red_s[0][wave] = su0; red_s[0][4 + wave] = ss0;
            red_s[1][wave] = su1; red_s[1][4 + wave] = ss1;
        }
    }
    __syncthreads();
    if (hid < 2) {
        float S  = red_s[hid][0] + red_s[hid][1] + red_s[hid][2] + red_s[hid][3];
        float SS = red_s[hid][4] + red_s[hid][5] + red_s[hid][6] + red_s[hid][7];
        float mu = S * (1.f / HID_);
        float var = SS * (1.f / HID_) - mu * mu;
        mu_rs[hid][0] = mu;
        mu_rs[hid][1] = rsqrtf(var + 1e-5f);
    }
    __syncthreads();

    float g = ln_g[hid], bb = ln_b[hid], hasb = has[b];
    float out0 = ((acc0 - mu_rs[0][0]) * mu_rs[0][1] * g + bb) * hasb;
    float out1 = ((acc1 - mu_rs[1][0]) * mu_rs[1][1] * g + bb) * hasb;
    seq_out[((size_t)(b * Q_ + qb * 2 + 0)) * HID_ + hid] = out0;
    seq_out[((size_t)(b * Q_ + qb * 2 + 1)) * HID_ + hid] = out1;
    atomicAdd(&pooled[b * HID_ + hid], (out0 + out1) * (1.f / (float)Q_));
}

// ---------------------------------------------------------------------------
extern "C" void kernel_launch(void* const* d_in, const int* in_sizes, int n_in,
                              void* d_out, int out_size, void* d_ws, size_t ws_size,
                              hipStream_t stream)
{
    const float* values = (const float*)d_in[0];
    const int*   mask   = (const int*)  d_in[1];
    const float* times  = (const float*)d_in[2];
    const float* w_per  = (const float*)d_in[3];
    const float* b_per  = (const float*)d_in[4];
    const float* w_lin  = (const float*)d_in[5];
    const float* b_lin  = (const float*)d_in[6];
    const float* wq     = (const float*)d_in[7];
    const float* bq     = (const float*)d_in[8];
    const float* wk     = (const float*)d_in[9];
    const float* bk     = (const float*)d_in[10];
    const float* wo     = (const float*)d_in[11];
    const float* bo     = (const float*)d_in[12];
    const float* ln_g   = (const float*)d_in[13];
    const float* ln_b   = (const float*)d_in[14];

    float* out     = (float*)d_out;
    float* seq_out = out;                        // B*Q*HID = 262144
    float* pooled  = out + 262144;               // B*HID   = 2048
    float* qt_out  = out + 262144 + 2048;        // B*Q     = 1024

    float* ws         = (float*)d_ws;
    float*    tn      = ws;                      // 2048
    float*    has     = ws + 2048;               // 8
    float*    cm      = ws + 2056;               // 256
    float*    colmean = ws + 2312;               // 256
    float*    qproj   = ws + 2568;               // 16384  (byte 10272, 16B-aligned)
    unsigned* bitsT   = (unsigned*)(ws + 18952); // 2048 u32
    float*    mvm     = ws + 21000;              // 65536  (byte 84000, 16B-aligned)
    float*    kproj   = ws + 86536;              // 262144 (byte 346144, 16B-aligned)
    float*    cvec    = ws + 348680;             // 2048
    float*    wotv    = ws + 350728;             // 65536 -> end 416264 f32 = 1.67 MB

    k_prep1<<<B_,               256, 0, stream>>>(values, mask, times,
                 tn, has, cm, colmean, mvm, bitsT, qt_out, pooled);
    k_prep2<<<392,              256, 0, stream>>>(tn, cm, w_per, b_per, w_lin, b_lin,
                 wq, bq, wk, bk, wo, bo, qproj, kproj, wotv, cvec);
    k_main <<<dim3(Q_ / 2, B_), 256, 0, stream>>>(qproj, kproj, mvm, bitsT,
                 cm, colmean, wotv, cvec, has, ln_g, ln_b, seq_out, pooled);
}